// Round 9
// baseline (219.646 us; speedup 1.0000x reference)
//
#include <hip/hip_runtime.h>
#include <hip/hip_fp16.h>

#define B_   8
#define CIN  256
#define T_   4096
#define TP   4097    // padded T (row 0 = zeros, row t+1 = x[t])
#define CO   256
#define O4   1024
#define NN   32768   // B_*T_
#define NCH  128     // chunks along T
#define CL   32      // chunk length

// ws layout (float offsets)
#define OFF_XHI  0           // ushort [8][4097][256]
#define OFF_XLO  4195328
#define OFF_WHI  8390656     // ushort [1024][512]
#define OFF_WLO  8652800
#define OFF_F16  8914944     // ushort(f16) [8][4096][256]
#define OFF_IZ16 13109248
#define OFF_O16  17303552
#define OFF_A    21497856    // float [8][128][256]
#define OFF_B    21760000

typedef __attribute__((ext_vector_type(8))) short short8;
typedef __attribute__((ext_vector_type(4))) float floatx4;

__device__ __forceinline__ float fsig(float x)  { return 1.0f / (1.0f + __expf(-x)); }
__device__ __forceinline__ float ftanh(float x) { return 2.0f / (1.0f + __expf(-2.0f * x)) - 1.0f; }

__device__ __forceinline__ unsigned short bf16_rne(float v) {
    unsigned u = __float_as_uint(v);
    unsigned r = (u + 0x7fffu + ((u >> 16) & 1u)) >> 16;
    return (unsigned short)r;
}
__device__ __forceinline__ void split_bf16(float v, unsigned short& hi, unsigned short& lo) {
    hi = bf16_rne(v);
    float hf = __uint_as_float(((unsigned)hi) << 16);
    lo = bf16_rne(v - hf);
}

// async 16B/lane global->LDS DMA; lds base must be wave-uniform (dest = base + lane*16)
__device__ __forceinline__ void glds16(const unsigned short* g, unsigned short* l) {
    __builtin_amdgcn_global_load_lds(
        (const __attribute__((address_space(1))) unsigned*)g,
        (__attribute__((address_space(3))) unsigned*)l, 16, 0, 0);
}

// merged converts: bid<2048 -> W repack/split; bid>=2048 -> X transpose/split.
// W[o=g*256+c][i][j] -> Wa[r=c*4+g][k=j*256+i].  x[b][c][t] -> Xpad[b][t+1][c].
__global__ void convert_kernel(const float* __restrict__ W,
                               const float* __restrict__ x,
                               unsigned short* __restrict__ Whi,
                               unsigned short* __restrict__ Wlo,
                               unsigned short* __restrict__ Xhi,
                               unsigned short* __restrict__ Xlo) {
    __shared__ float tile[64][69];      // 69 mod 32 = 5 -> conflict-free both phases
    const int bid = blockIdx.x;
    const int tid = threadIdx.x;
    if (bid < 2048) {
        int e = bid * 256 + tid;        // 1024*512 elements
        int r = e >> 9, k = e & 511;
        int g = r & 3, c = r >> 2;
        int j = k >> 8, i = k & 255;
        float v = W[((size_t)((g << 8) + c)) * 512 + i * 2 + j];
        unsigned short hi, lo;
        split_bf16(v, hi, lo);
        Whi[e] = hi;
        Wlo[e] = lo;
        return;
    }
    const int b2 = bid - 2048;
    const int t0 = (b2 & 63) * 64;
    const int c0 = ((b2 >> 6) & 3) * 64;
    const int b  = b2 >> 8;

    {   // read: float4 along t, 16 rows per pass
        int j4 = (tid & 15) * 4, r16 = tid >> 4;
#pragma unroll
        for (int p = 0; p < 4; p++) {
            int i = p * 16 + r16;
            float4 v = *(const float4*)&x[((size_t)(b * 256 + c0 + i)) * T_ + t0 + j4];
            tile[i][j4] = v.x; tile[i][j4 + 1] = v.y;
            tile[i][j4 + 2] = v.z; tile[i][j4 + 3] = v.w;
        }
    }
    if (t0 == 0 && tid < 64) {   // zero pad row (x[-1] = 0)
        size_t z = (size_t)b * TP * 256 + c0 + tid;
        Xhi[z] = 0; Xlo[z] = 0;
    }
    __syncthreads();
    {   // write: 4 consecutive channels per thread, packed uint2 (8B) stores
        const int cslot = tid & 15, trow = tid >> 4;
#pragma unroll
        for (int p = 0; p < 4; p++) {
            int t = p * 16 + trow;
            unsigned hi0, hi1, lo0, lo1;
            {
                unsigned short h, l;
                split_bf16(tile[cslot * 4 + 0][t], h, l);
                hi0 = h; lo0 = l;
                split_bf16(tile[cslot * 4 + 1][t], h, l);
                hi0 |= ((unsigned)h) << 16; lo0 |= ((unsigned)l) << 16;
                split_bf16(tile[cslot * 4 + 2][t], h, l);
                hi1 = h; lo1 = l;
                split_bf16(tile[cslot * 4 + 3][t], h, l);
                hi1 |= ((unsigned)h) << 16; lo1 |= ((unsigned)l) << 16;
            }
            size_t idx = ((size_t)b * TP + t0 + t + 1) * 256 + c0 + cslot * 4;
            uint2 ph; ph.x = hi0; ph.y = hi1;
            uint2 pl; pl.x = lo0; pl.y = lo1;
            *(uint2*)&Xhi[idx] = ph;
            *(uint2*)&Xlo[idx] = pl;
        }
    }
}

// C[r=1024][n=32768] = Wa · Xb^T, split-bf16 MFMA (3 products).
// Round 9: 256x128 tile, 8 waves (4M x 2N) of 64x64 (read:MFMA 0.33 vs R7's
// 0.5), XOR swizzle (R7-proven), 3-phase counted vmcnt, LDS 72 KiB:
// AH/BH double-buffered, AL/BL SINGLE-buffered (AL only read in P2, BL only
// in P1; refills ordered by the existing end-of-phase barriers):
//   AL_i  issued at P0(i)  (readers of AL_{i-1} done at end-P2(i-1) barrier)
//   BL_i+1 issued at P2(i) (readers of BL_i done at end-P1(i) barrier)
// FIFO ledger (P0 issue order AL, AH', BH'): prologue {AH,BH,BL}: vmcnt(1);
// end-P0 vmcnt(5) [BL_i in]; end-P1 vmcnt(3) [AL_i in]; end-P2 vmcnt(1)
// [AH',BH' in]. 2 blocks/CU (144 KiB), 16 waves/CU — R8's occupancy loss
// avoided while keeping its LDS-traffic reduction (163K -> ~123K cyc/CU).
// Planes (ushort idx): AH[d]=d*8192, BH[d]=16384+d*4096, AL=24576, BL=32768.
__launch_bounds__(512, 4)
__global__ void gemm_mfma_kernel(const unsigned short* __restrict__ Xhi,
                                 const unsigned short* __restrict__ Xlo,
                                 const unsigned short* __restrict__ Whi,
                                 const unsigned short* __restrict__ Wlo,
                                 const float* __restrict__ bias,
                                 __half* __restrict__ fw,
                                 __half* __restrict__ izw,
                                 __half* __restrict__ ow,
                                 float* __restrict__ Aw,
                                 float* __restrict__ Bw)
{
    __shared__ unsigned short smem_us[36864];   // 72 KiB

    const int tid  = threadIdx.x;
    const int wave = tid >> 6, lane = tid & 63;   // 8 waves
    const int q = lane >> 4, mr = lane & 15;
    const int wm = wave >> 1, wn = wave & 1;      // 4 x 2 wave grid (M x N)

    // grid: 1024 = 8 xcd x (32 n-tiles x 4 r, r fastest -> X-tile L2-resident)
    const int bid   = blockIdx.x;
    const int xcd   = bid & 7;
    const int idx   = bid >> 3;                  // 0..127
    const int n_blk = xcd * 32 + (idx >> 2);     // 0..255
    const int r_blk = idx & 3;                   // 0..3
    const int r0 = r_blk * 256;
    const int n0 = n_blk * 128;
    const int bb = n0 >> 12;
    const int t0 = n0 & (T_ - 1);

    // staging lanes: 4 lanes/row, XOR-swizzled slice within the row's 64B
    const int lrow = lane >> 2;                              // 0..15
    const int lcol = (((lane & 3) ^ ((lrow >> 1) & 3)) * 8); // swizzled ushort offset
    // A: wave stages rows wave*32 + {0..15, 16..31}: 2 DMAs per plane
    const size_t wAoff = (size_t)(r0 + wave * 32 + lrow) * 512 + lcol;
    const unsigned short* pWh0 = Whi + wAoff;
    const unsigned short* pWh1 = pWh0 + 16 * 512;
    const unsigned short* pWl0 = Wlo + wAoff;
    const unsigned short* pWl1 = pWl0 + 16 * 512;
    // B: wave stages rows wave*16 + {0..15}: 1 DMA per plane
    const size_t xBoff = ((size_t)bb * TP + t0 + wave * 16 + lrow) * 256 + lcol;
    const unsigned short* pXh = Xhi + xBoff;
    const unsigned short* pXl = Xlo + xBoff;

    // fragment read bases (swizzled slice); rows 16-aligned => same XOR phase
    const int swz = (q ^ ((mr >> 1) & 3)) * 8;
    const int aoffb = (wm * 64 + mr) * 32 + swz;   // + v*512, v=0..3
    const int boffb = (wn * 64 + mr) * 32 + swz;   // + u*512, u=0..3
    const int wstA = wave * 1024;                  // wave offset in A planes
    const int wstB = wave * 512;                   // wave offset in B planes

    unsigned short* const ALp = smem_us + 24576;
    unsigned short* const BLp = smem_us + 32768;

    floatx4 acc[4][4];
#pragma unroll
    for (int v = 0; v < 4; v++)
#pragma unroll
        for (int u = 0; u < 4; u++) acc[v][u] = (floatx4){0.f, 0.f, 0.f, 0.f};

    // prologue: AH(2), BH(1) into buf0; BL_0(1). AL_0 issued in P0(0).
    glds16(pWh0, smem_us + wstA);  glds16(pWh1, smem_us + wstA + 512);
    glds16(pXh,  smem_us + 16384 + wstB);
    glds16(pXl,  BLp + wstB);
    asm volatile("s_waitcnt vmcnt(1)" ::: "memory");   // AH,BH landed; BL in flight
    __builtin_amdgcn_s_barrier();
    __builtin_amdgcn_sched_barrier(0);

#pragma unroll 2
    for (int i = 0; i < 16; ++i) {
        const int cur = i & 1, nxt = cur ^ 1;
        const unsigned kkc = (unsigned)(i * 32);             // this iter (AL)
        const unsigned kkn = (unsigned)(((i + 1) & 15) * 32);// next iter (AH',BH',BL')
        const unsigned short* AHc = smem_us + cur * 8192;
        const unsigned short* BHc = smem_us + 16384 + cur * 4096;
        unsigned short* dAH = smem_us + nxt * 8192 + wstA;
        unsigned short* dBH = smem_us + 16384 + nxt * 4096 + wstB;

        short8 ah[4], bh[4];

        // ---------- P0: hi*hi ----------
#pragma unroll
        for (int v = 0; v < 4; ++v) ah[v] = *(const short8*)(AHc + aoffb + v * 512);
#pragma unroll
        for (int u = 0; u < 4; ++u) bh[u] = *(const short8*)(BHc + boffb + u * 512);
        // issue order matters for the ledger: AL_i first, then AH', BH'
        glds16(pWl0 + kkc, ALp + wstA); glds16(pWl1 + kkc, ALp + wstA + 512);
        glds16(pWh0 + kkn, dAH);        glds16(pWh1 + kkn, dAH + 512);
        glds16(pXh + kkn, dBH);
        asm volatile("s_waitcnt lgkmcnt(0)" ::: "memory");
        __builtin_amdgcn_sched_barrier(0);
        __builtin_amdgcn_s_setprio(1);
#pragma unroll
        for (int v = 0; v < 4; ++v)
#pragma unroll
            for (int u = 0; u < 4; ++u)
                acc[v][u] = __builtin_amdgcn_mfma_f32_16x16x32_bf16(ah[v], bh[u], acc[v][u], 0, 0, 0);
        __builtin_amdgcn_s_setprio(0);
        asm volatile("s_waitcnt vmcnt(5)" ::: "memory");   // BL_i landed
        __builtin_amdgcn_s_barrier();
        __builtin_amdgcn_sched_barrier(0);

        // ---------- P1: hi*lo ----------
        {
            short8 bl[4];
#pragma unroll
            for (int u = 0; u < 4; ++u) bl[u] = *(const short8*)(BLp + boffb + u * 512);
            asm volatile("s_waitcnt lgkmcnt(0)" ::: "memory");
            __builtin_amdgcn_sched_barrier(0);
            __builtin_amdgcn_s_setprio(1);
#pragma unroll
            for (int v = 0; v < 4; ++v)
#pragma unroll
                for (int u = 0; u < 4; ++u)
                    acc[v][u] = __builtin_amdgcn_mfma_f32_16x16x32_bf16(ah[v], bl[u], acc[v][u], 0, 0, 0);
            __builtin_amdgcn_s_setprio(0);
        }
        asm volatile("s_waitcnt vmcnt(3)" ::: "memory");   // AL_i landed
        __builtin_amdgcn_s_barrier();
        __builtin_amdgcn_sched_barrier(0);

        // ---------- P2: lo*hi ----------
        {
            short8 al[4];
#pragma unroll
            for (int v = 0; v < 4; ++v) al[v] = *(const short8*)(ALp + aoffb + v * 512);
            glds16(pXl + kkn, BLp + wstB);   // BL_{i+1}: readers of BL_i done (end-P1 barrier)
            asm volatile("s_waitcnt lgkmcnt(0)" ::: "memory");
            __builtin_amdgcn_sched_barrier(0);
            __builtin_amdgcn_s_setprio(1);
#pragma unroll
            for (int v = 0; v < 4; ++v)
#pragma unroll
                for (int u = 0; u < 4; ++u)
                    acc[v][u] = __builtin_amdgcn_mfma_f32_16x16x32_bf16(al[v], bh[u], acc[v][u], 0, 0, 0);
            __builtin_amdgcn_s_setprio(0);
        }
        asm volatile("s_waitcnt vmcnt(1)" ::: "memory");   // AH',BH' landed
        __builtin_amdgcn_s_barrier();
        __builtin_amdgcn_sched_barrier(0);
    }

    // ---------- epilogue ----------
    asm volatile("s_waitcnt vmcnt(0)" ::: "memory");   // drain wrap-staging junk DMAs
    __syncthreads();                     // LDS reused below
    __half* epf = (__half*)smem_us;      // [128 t][72] f16 (64 ch + pad), 144B rows
    __half* epz = epf + 128 * 72;
    __half* epo = epz + 128 * 72;        // total 55,296 B < 72 KiB
    const int ch_base = r0 >> 2;         // 64 channels per block

#pragma unroll
    for (int v = 0; v < 4; ++v) {
        const int cl = wm * 16 + v * 4 + q;          // local channel 0..63
        const int ch = ch_base + cl;
        const float bz  = bias[ch];
        const float bf_ = bias[256 + ch];
        const float bo  = bias[512 + ch];
        const float bi  = bias[768 + ch];
#pragma unroll
        for (int u = 0; u < 4; ++u) {
            const int t_l = wn * 64 + u * 16 + mr;   // local t 0..127
            float zv = ftanh(acc[v][u][0] + bz);
            float fv = fsig(acc[v][u][1] + bf_);
            float ov = fsig(acc[v][u][2] + bo);
            float iv = fsig(acc[v][u][3] + bi);
            const int off = t_l * 72 + cl;
            epf[off] = __float2half(fv);             // same f16 rounding as before
            epz[off] = __float2half(iv * zv);
            epo[off] = __float2half(ov);
        }
    }
    __syncthreads();

    // coalesced f16 stores: 4 threads per t-row, 16 channels (32B) each
    {
        const int t_r = tid >> 2;                    // 0..127
        const int c16 = (tid & 3) << 4;              // 0,16,32,48
        const size_t gbase = ((size_t)bb * T_ + t0 + t_r) * 256 + ch_base + c16;
        const int lb = t_r * 72 + c16;               // 16B-aligned (144|16, 32|16)
        {
            const uint4* s = (const uint4*)&epf[lb];
            uint4* d = (uint4*)&fw[gbase];
            d[0] = s[0]; d[1] = s[1];
        }
        {
            const uint4* s = (const uint4*)&epz[lb];
            uint4* d = (uint4*)&izw[gbase];
            d[0] = s[0]; d[1] = s[1];
        }
        {
            const uint4* s = (const uint4*)&epo[lb];
            uint4* d = (uint4*)&ow[gbase];
            d[0] = s[0]; d[1] = s[1];
        }
    }

    // fused scan phase 1: per-chunk (A = prod f, B = affine end); 4 chunks x 64 ch
    if (tid < 256) {
        const int chunk = tid >> 6;                  // 0..3
        const int c = tid & 63;
        float A = 1.0f, Bv = 0.0f;
        const int base = (chunk * 32) * 72 + c;
#pragma unroll 4
        for (int j = 0; j < 32; ++j) {
            float f  = __half2float(epf[base + j * 72]);
            float iz = __half2float(epz[base + j * 72]);
            Bv = fmaf(f, Bv, iz);
            A *= f;
        }
        const int chunk_abs = (t0 >> 5) + chunk;
        const size_t aidx = ((size_t)bb * NCH + chunk_abs) * 256 + ch_base + c;
        Aw[aidx] = A;
        Bw[aidx] = Bv;
    }
}

// Phase 3 (merged with old phase 2): each block computes its own carry from
// the chunk summaries (predicated 16-wide batched loads; Aw/Bw are L2-hot
// 256KB), then replays the recurrence and writes out[b][c][t] transposed.
__global__ void scan_phase3(const __half* __restrict__ fw, const __half* __restrict__ izw,
                            const __half* __restrict__ ow,
                            const float* __restrict__ Aw, const float* __restrict__ Bw,
                            float* __restrict__ out)
{
    __shared__ float hbuf[CL][257];
    __shared__ float carry_s[256];
    int b = blockIdx.y, ch = blockIdx.x;
    int tid = threadIdx.x;

    {   // carry over chunks 0..ch-1 for channel tid (exclusive scan, batched)
        const int c = tid;
        float carry = 0.0f;
        for (int g = 0; g < 8; ++g) {
            if (g * 16 >= ch) break;
            float Ar[16], Br[16];
#pragma unroll
            for (int j = 0; j < 16; ++j) {
                int jj = g * 16 + j;
                bool ok = jj < ch;
                size_t idx2 = ((size_t)(b * NCH + (ok ? jj : 0))) * CO + c;
                Ar[j] = ok ? Aw[idx2] : 1.0f;
                Br[j] = ok ? Bw[idx2] : 0.0f;
            }
#pragma unroll
            for (int j = 0; j < 16; ++j) carry = fmaf(Ar[j], carry, Br[j]);
        }
        carry_s[c] = carry;
    }
    __syncthreads();

    if (tid < 128) {
        const int c2 = tid * 2;
        float cs0 = carry_s[c2];
        float cs1 = carry_s[c2 + 1];
        size_t base = ((size_t)(b * T_ + ch * CL)) * CO + c2;
#pragma unroll 4
        for (int tt = 0; tt < CL; tt++) {
            __half2 f2  = *(const __half2*)&fw [base + (size_t)tt * CO];
            __half2 iz2 = *(const __half2*)&izw[base + (size_t)tt * CO];
            __half2 o2  = *(const __half2*)&ow [base + (size_t)tt * CO];
            float2 f  = __half22float2(f2);
            float2 iz = __half22float2(iz2);
            float2 o  = __half22float2(o2);
            cs0 = fmaf(f.x, cs0, iz.x);
            cs1 = fmaf(f.y, cs1, iz.y);
            hbuf[tt][c2]     = o.x * cs0;
            hbuf[tt][c2 + 1] = o.y * cs1;
        }
    }
    __syncthreads();
    int tt = threadIdx.x & 31;
    int cr = threadIdx.x >> 5;
#pragma unroll
    for (int w = 0; w < 32; w++) {
        int cc = cr + w * 8;
        out[((size_t)(b * CO + cc)) * T_ + ch * CL + tt] = hbuf[tt][cc];
    }
}

extern "C" void kernel_launch(void* const* d_in, const int* in_sizes, int n_in,
                              void* d_out, int out_size, void* d_ws, size_t ws_size,
                              hipStream_t stream) {
    const float* x    = (const float*)d_in[0];
    const float* W    = (const float*)d_in[1];
    const float* bias = (const float*)d_in[2];
    float* out = (float*)d_out;
    float* ws  = (float*)d_ws;

    unsigned short* Xhi = (unsigned short*)(ws + OFF_XHI);
    unsigned short* Xlo = (unsigned short*)(ws + OFF_XLO);
    unsigned short* Whi = (unsigned short*)(ws + OFF_WHI);
    unsigned short* Wlo = (unsigned short*)(ws + OFF_WLO);
    __half* fw  = (__half*)(ws + OFF_F16);
    __half* izw = (__half*)(ws + OFF_IZ16);
    __half* ow  = (__half*)(ws + OFF_O16);
    float* Aw  = ws + OFF_A;
    float* Bw  = ws + OFF_B;

    convert_kernel<<<4096, 256, 0, stream>>>(W, x, Whi, Wlo, Xhi, Xlo);
    gemm_mfma_kernel<<<(NN / 128) * (O4 / 256), 512, 0, stream>>>(
        Xhi, Xlo, Whi, Wlo, bias, fw, izw, ow, Aw, Bw);
    scan_phase3<<<dim3(NCH, B_), CO, 0, stream>>>(fw, izw, ow, Aw, Bw, out);
}

// Round 10
// 215.496 us; speedup vs baseline: 1.0193x; 1.0193x over previous
//
#include <hip/hip_runtime.h>
#include <hip/hip_fp16.h>

#define B_   8
#define CIN  256
#define T_   4096
#define TP   4097    // padded T (row 0 = zeros, row t+1 = x[t])
#define CO   256
#define O4   1024
#define NN   32768   // B_*T_
#define NCH  128     // chunks along T
#define CL   32      // chunk length

// ws layout (float offsets)
#define OFF_XHI  0           // ushort [8][4097][256]
#define OFF_XLO  4195328
#define OFF_WHI  8390656     // ushort [1024][512]
#define OFF_WLO  8652800
#define OFF_F16  8914944     // ushort(f16) [8][4096][256]
#define OFF_IZ16 13109248
#define OFF_O16  17303552
#define OFF_A    21497856    // float [8][128][256]
#define OFF_B    21760000

typedef __attribute__((ext_vector_type(8))) short short8;
typedef __attribute__((ext_vector_type(4))) float floatx4;

__device__ __forceinline__ float fsig(float x)  { return 1.0f / (1.0f + __expf(-x)); }
__device__ __forceinline__ float ftanh(float x) { return 2.0f / (1.0f + __expf(-2.0f * x)) - 1.0f; }

__device__ __forceinline__ unsigned short bf16_rne(float v) {
    unsigned u = __float_as_uint(v);
    unsigned r = (u + 0x7fffu + ((u >> 16) & 1u)) >> 16;
    return (unsigned short)r;
}
__device__ __forceinline__ void split_bf16(float v, unsigned short& hi, unsigned short& lo) {
    hi = bf16_rne(v);
    float hf = __uint_as_float(((unsigned)hi) << 16);
    lo = bf16_rne(v - hf);
}

// async 16B/lane global->LDS DMA; lds base must be wave-uniform (dest = base + lane*16)
__device__ __forceinline__ void glds16(const unsigned short* g, unsigned short* l) {
    __builtin_amdgcn_global_load_lds(
        (const __attribute__((address_space(1))) unsigned*)g,
        (__attribute__((address_space(3))) unsigned*)l, 16, 0, 0);
}

// merged converts: bid<2048 -> W repack/split; bid>=2048 -> X transpose/split.
// W[o=g*256+c][i][j] -> Wa[r=c*4+g][k=j*256+i].  x[b][c][t] -> Xpad[b][t+1][c].
__global__ void convert_kernel(const float* __restrict__ W,
                               const float* __restrict__ x,
                               unsigned short* __restrict__ Whi,
                               unsigned short* __restrict__ Wlo,
                               unsigned short* __restrict__ Xhi,
                               unsigned short* __restrict__ Xlo) {
    __shared__ float tile[64][69];      // 69 mod 32 = 5 -> conflict-free both phases
    const int bid = blockIdx.x;
    const int tid = threadIdx.x;
    if (bid < 2048) {
        int e = bid * 256 + tid;        // 1024*512 elements
        int r = e >> 9, k = e & 511;
        int g = r & 3, c = r >> 2;
        int j = k >> 8, i = k & 255;
        float v = W[((size_t)((g << 8) + c)) * 512 + i * 2 + j];
        unsigned short hi, lo;
        split_bf16(v, hi, lo);
        Whi[e] = hi;
        Wlo[e] = lo;
        return;
    }
    const int b2 = bid - 2048;
    const int t0 = (b2 & 63) * 64;
    const int c0 = ((b2 >> 6) & 3) * 64;
    const int b  = b2 >> 8;

    {   // read: float4 along t, 16 rows per pass
        int j4 = (tid & 15) * 4, r16 = tid >> 4;
#pragma unroll
        for (int p = 0; p < 4; p++) {
            int i = p * 16 + r16;
            float4 v = *(const float4*)&x[((size_t)(b * 256 + c0 + i)) * T_ + t0 + j4];
            tile[i][j4] = v.x; tile[i][j4 + 1] = v.y;
            tile[i][j4 + 2] = v.z; tile[i][j4 + 3] = v.w;
        }
    }
    if (t0 == 0 && tid < 64) {   // zero pad row (x[-1] = 0)
        size_t z = (size_t)b * TP * 256 + c0 + tid;
        Xhi[z] = 0; Xlo[z] = 0;
    }
    __syncthreads();
    {   // write: 4 consecutive channels per thread, packed uint2 (8B) stores
        const int cslot = tid & 15, trow = tid >> 4;
#pragma unroll
        for (int p = 0; p < 4; p++) {
            int t = p * 16 + trow;
            unsigned hi0, hi1, lo0, lo1;
            {
                unsigned short h, l;
                split_bf16(tile[cslot * 4 + 0][t], h, l);
                hi0 = h; lo0 = l;
                split_bf16(tile[cslot * 4 + 1][t], h, l);
                hi0 |= ((unsigned)h) << 16; lo0 |= ((unsigned)l) << 16;
                split_bf16(tile[cslot * 4 + 2][t], h, l);
                hi1 = h; lo1 = l;
                split_bf16(tile[cslot * 4 + 3][t], h, l);
                hi1 |= ((unsigned)h) << 16; lo1 |= ((unsigned)l) << 16;
            }
            size_t idx = ((size_t)b * TP + t0 + t + 1) * 256 + c0 + cslot * 4;
            uint2 ph; ph.x = hi0; ph.y = hi1;
            uint2 pl; pl.x = lo0; pl.y = lo1;
            *(uint2*)&Xhi[idx] = ph;
            *(uint2*)&Xlo[idx] = pl;
        }
    }
}

// C[r=1024][n=32768] = Wa · Xb^T, split-bf16 MFMA (3 products).
// Round 10 = R7 exactly (128x128, BK=32, XOR swizzle, 3-phase counted vmcnt,
// R7 grid map / FETCH=32MB) with LDS cut 64 -> 48 KiB: AH/BH double-buffered,
// AL/BL SINGLE-buffered (AL read only in P2, BL only in P1; R9-proven sync):
//   AL_i   issued in P0(i)  (readers of AL_{i-1} done at end-P2(i-1) barrier)
//   BL_i+1 issued in P2(i)  (readers of BL_i done at end-P1(i) barrier)
// -> 3 blocks/CU, 24 waves/CU (R7 had 2 blk / 16 waves; occupancy ladder
// 1blk=119.5, 2blk=111.2 us). FIFO ledger (P0 issues AL_i,AH',BH'; P2
// issues BL'): prologue {AH,BH,BL} vmcnt(1); end-P0 vmcnt(3) [BL_i in];
// end-P1 vmcnt(2) [AL_i in]; end-P2 vmcnt(1) [AH',BH' in].
// Planes (ushort idx): AH[d]=d*4096, BH[d]=8192+d*4096, AL=16384, BL=20480.
__launch_bounds__(512, 6)
__global__ void gemm_mfma_kernel(const unsigned short* __restrict__ Xhi,
                                 const unsigned short* __restrict__ Xlo,
                                 const unsigned short* __restrict__ Whi,
                                 const unsigned short* __restrict__ Wlo,
                                 const float* __restrict__ bias,
                                 __half* __restrict__ fw,
                                 __half* __restrict__ izw,
                                 __half* __restrict__ ow,
                                 float* __restrict__ Aw,
                                 float* __restrict__ Bw)
{
    __shared__ unsigned short smem_us[24576];   // 48 KiB

    const int tid  = threadIdx.x;
    const int wave = tid >> 6, lane = tid & 63;
    const int q = lane >> 4, mr = lane & 15;
    const int wm = wave >> 2, wn = wave & 3;     // 2 x 4 wave grid (M x N)

    // grid: 2048 = 8 xcd x (32 n-tiles x 8 r, r fastest -> X-tile L2-resident)
    const int bid   = blockIdx.x;
    const int xcd   = bid & 7;
    const int idx   = bid >> 3;                  // 0..255
    const int n_blk = xcd * 32 + (idx >> 3);     // 0..255
    const int r_blk = idx & 7;                   // 0..7
    const int r0 = r_blk * 128;
    const int n0 = n_blk * 128;
    const int bb = n0 >> 12;
    const int t0 = n0 & (T_ - 1);

    // staging: wave w stages rows w*16..w*16+15 of each plane; 1 DMA per plane.
    // XOR-swizzled source slice (within the row's contiguous 64B window).
    const int lrow = lane >> 2;                              // 0..15
    const int lcol = (((lane & 3) ^ ((lrow >> 1) & 3)) * 8); // swizzled ushort offset
    const size_t wAoff = (size_t)(r0 + wave * 16 + lrow) * 512 + lcol;
    const unsigned short* pWh = Whi + wAoff;
    const unsigned short* pWl = Wlo + wAoff;
    const size_t xBoff = ((size_t)bb * TP + t0 + wave * 16 + lrow) * 256 + lcol;
    const unsigned short* pXh = Xhi + xBoff;
    const unsigned short* pXl = Xlo + xBoff;

    // fragment read bases (ushort offsets within one plane, swizzled slice)
    const int swz = (q ^ ((mr >> 1) & 3)) * 8;
    const int aoffb = (wm * 64 + mr) * 32 + swz;   // + v*512
    const int boffb = (wn * 32 + mr) * 32 + swz;   // + u*512
    const int wst = wave * 512;                  // wave staging offset in plane

    unsigned short* const ALp = smem_us + 16384;
    unsigned short* const BLp = smem_us + 20480;

    floatx4 acc[4][2];
#pragma unroll
    for (int v = 0; v < 4; v++)
#pragma unroll
        for (int u = 0; u < 2; u++) acc[v][u] = (floatx4){0.f, 0.f, 0.f, 0.f};

    // prologue: AH,BH into buf0; BL_0. AL_0 issued in P0(0).
    glds16(pWh, smem_us + wst);
    glds16(pXh, smem_us + 8192 + wst);
    glds16(pXl, BLp + wst);
    asm volatile("s_waitcnt vmcnt(1)" ::: "memory");   // AH,BH landed; BL_0 in flight
    __builtin_amdgcn_s_barrier();
    __builtin_amdgcn_sched_barrier(0);

#pragma unroll 2
    for (int i = 0; i < 16; ++i) {
        const int cur = i & 1, nxt = cur ^ 1;
        const unsigned kkc = (unsigned)(i * 32);              // this iter (AL)
        const unsigned kkn = (unsigned)(((i + 1) & 15) * 32); // next iter (AH',BH',BL')
        const unsigned short* AHc = smem_us + cur * 4096;
        const unsigned short* BHc = smem_us + 8192 + cur * 4096;
        unsigned short* dAH = smem_us + nxt * 4096 + wst;
        unsigned short* dBH = smem_us + 8192 + nxt * 4096 + wst;

        short8 ah[4], bh[2];

        // ---------- P0: hi*hi ----------
#pragma unroll
        for (int v = 0; v < 4; ++v) ah[v] = *(const short8*)(AHc + aoffb + v * 512);
#pragma unroll
        for (int u = 0; u < 2; ++u) bh[u] = *(const short8*)(BHc + boffb + u * 512);
        // issue order fixes the ledger: AL_i first, then AH', BH'
        glds16(pWl + kkc, ALp + wst);
        glds16(pWh + kkn, dAH);
        glds16(pXh + kkn, dBH);
        asm volatile("s_waitcnt lgkmcnt(0)" ::: "memory");
        __builtin_amdgcn_sched_barrier(0);
        __builtin_amdgcn_s_setprio(1);
#pragma unroll
        for (int v = 0; v < 4; ++v)
#pragma unroll
            for (int u = 0; u < 2; ++u)
                acc[v][u] = __builtin_amdgcn_mfma_f32_16x16x32_bf16(ah[v], bh[u], acc[v][u], 0, 0, 0);
        __builtin_amdgcn_s_setprio(0);
        asm volatile("s_waitcnt vmcnt(3)" ::: "memory");   // BL_i landed
        __builtin_amdgcn_s_barrier();
        __builtin_amdgcn_sched_barrier(0);

        // ---------- P1: hi*lo ----------
        {
            short8 bl[2];
#pragma unroll
            for (int u = 0; u < 2; ++u) bl[u] = *(const short8*)(BLp + boffb + u * 512);
            asm volatile("s_waitcnt lgkmcnt(0)" ::: "memory");
            __builtin_amdgcn_sched_barrier(0);
            __builtin_amdgcn_s_setprio(1);
#pragma unroll
            for (int v = 0; v < 4; ++v)
#pragma unroll
                for (int u = 0; u < 2; ++u)
                    acc[v][u] = __builtin_amdgcn_mfma_f32_16x16x32_bf16(ah[v], bl[u], acc[v][u], 0, 0, 0);
            __builtin_amdgcn_s_setprio(0);
        }
        asm volatile("s_waitcnt vmcnt(2)" ::: "memory");   // AL_i landed
        __builtin_amdgcn_s_barrier();
        __builtin_amdgcn_sched_barrier(0);

        // ---------- P2: lo*hi ----------
        {
            short8 al[4];
#pragma unroll
            for (int v = 0; v < 4; ++v) al[v] = *(const short8*)(ALp + aoffb + v * 512);
            glds16(pXl + kkn, BLp + wst);   // BL_{i+1}: BL_i readers done (end-P1 barrier)
            asm volatile("s_waitcnt lgkmcnt(0)" ::: "memory");
            __builtin_amdgcn_sched_barrier(0);
            __builtin_amdgcn_s_setprio(1);
#pragma unroll
            for (int v = 0; v < 4; ++v)
#pragma unroll
                for (int u = 0; u < 2; ++u)
                    acc[v][u] = __builtin_amdgcn_mfma_f32_16x16x32_bf16(al[v], bh[u], acc[v][u], 0, 0, 0);
            __builtin_amdgcn_s_setprio(0);
        }
        asm volatile("s_waitcnt vmcnt(1)" ::: "memory");   // AH',BH' landed
        __builtin_amdgcn_s_barrier();
        __builtin_amdgcn_sched_barrier(0);
    }

    // ---------- epilogue ----------
    asm volatile("s_waitcnt vmcnt(0)" ::: "memory");   // drain wrap-staging junk DMAs
    __syncthreads();                     // LDS reused below
    __half* epf = (__half*)smem_us;      // [128][36] f16, 72B rows (conflict-free t-phase)
    __half* epz = epf + 128 * 36;
    __half* epo = epz + 128 * 36;        // total 27,648 B < 48 KiB
    const int ch_base = r0 >> 2;         // 32 channels per block

#pragma unroll
    for (int v = 0; v < 4; ++v) {
        const int cl = wm * 16 + v * 4 + q;          // local channel 0..31
        const int ch = ch_base + cl;
        const float bz  = bias[ch];
        const float bf_ = bias[256 + ch];
        const float bo  = bias[512 + ch];
        const float bi  = bias[768 + ch];
#pragma unroll
        for (int u = 0; u < 2; ++u) {
            const int t_l = wn * 32 + u * 16 + mr;   // local t 0..127
            float zv = ftanh(acc[v][u][0] + bz);
            float fv = fsig(acc[v][u][1] + bf_);
            float ov = fsig(acc[v][u][2] + bo);
            float iv = fsig(acc[v][u][3] + bi);
            const int off = t_l * 36 + cl;
            epf[off] = __float2half(fv);             // same f16 rounding as before
            epz[off] = __float2half(iv * zv);
            epo[off] = __float2half(ov);
        }
    }
    __syncthreads();

    // coalesced f16 stores: 4 threads per t-row, 8 channels (16B) each
    {
        const int t_r = tid >> 2;                    // 0..127
        const int c8 = (tid & 3) << 3;               // 0,8,16,24
        const size_t gbase = ((size_t)bb * T_ + t0 + t_r) * 256 + ch_base + c8;
        const int lb = t_r * 36 + c8;                // 8B-aligned
        union { uint2 u2[2]; uint4 u4; } pk;
        pk.u2[0] = *(const uint2*)&epf[lb];
        pk.u2[1] = *(const uint2*)&epf[lb + 4];
        *(uint4*)&fw[gbase] = pk.u4;
        pk.u2[0] = *(const uint2*)&epz[lb];
        pk.u2[1] = *(const uint2*)&epz[lb + 4];
        *(uint4*)&izw[gbase] = pk.u4;
        pk.u2[0] = *(const uint2*)&epo[lb];
        pk.u2[1] = *(const uint2*)&epo[lb + 4];
        *(uint4*)&ow[gbase] = pk.u4;
    }

    // fused scan phase 1: per-chunk (A = prod f, B = affine end); 4 chunks x 32 ch
    if (tid < 128) {
        const int chunk = tid >> 5;                  // 0..3
        const int c = tid & 31;
        float A = 1.0f, Bv = 0.0f;
        const int base = (chunk * 32) * 36 + c;
#pragma unroll 4
        for (int j = 0; j < 32; ++j) {
            float f  = __half2float(epf[base + j * 36]);
            float iz = __half2float(epz[base + j * 36]);
            Bv = fmaf(f, Bv, iz);
            A *= f;
        }
        const int chunk_abs = (t0 >> 5) + chunk;
        const size_t aidx = ((size_t)bb * NCH + chunk_abs) * 256 + ch_base + c;
        Aw[aidx] = A;
        Bw[aidx] = Bv;
    }
}

// Phase 3 (merged with old phase 2): each block computes its own carry from
// the chunk summaries (predicated 16-wide batched loads; Aw/Bw are L2-hot
// 256KB), then replays the recurrence and writes out[b][c][t] transposed.
__global__ void scan_phase3(const __half* __restrict__ fw, const __half* __restrict__ izw,
                            const __half* __restrict__ ow,
                            const float* __restrict__ Aw, const float* __restrict__ Bw,
                            float* __restrict__ out)
{
    __shared__ float hbuf[CL][257];
    __shared__ float carry_s[256];
    int b = blockIdx.y, ch = blockIdx.x;
    int tid = threadIdx.x;

    {   // carry over chunks 0..ch-1 for channel tid (exclusive scan, batched)
        const int c = tid;
        float carry = 0.0f;
        for (int g = 0; g < 8; ++g) {
            if (g * 16 >= ch) break;
            float Ar[16], Br[16];
#pragma unroll
            for (int j = 0; j < 16; ++j) {
                int jj = g * 16 + j;
                bool ok = jj < ch;
                size_t idx2 = ((size_t)(b * NCH + (ok ? jj : 0))) * CO + c;
                Ar[j] = ok ? Aw[idx2] : 1.0f;
                Br[j] = ok ? Bw[idx2] : 0.0f;
            }
#pragma unroll
            for (int j = 0; j < 16; ++j) carry = fmaf(Ar[j], carry, Br[j]);
        }
        carry_s[c] = carry;
    }
    __syncthreads();

    if (tid < 128) {
        const int c2 = tid * 2;
        float cs0 = carry_s[c2];
        float cs1 = carry_s[c2 + 1];
        size_t base = ((size_t)(b * T_ + ch * CL)) * CO + c2;
#pragma unroll 4
        for (int tt = 0; tt < CL; tt++) {
            __half2 f2  = *(const __half2*)&fw [base + (size_t)tt * CO];
            __half2 iz2 = *(const __half2*)&izw[base + (size_t)tt * CO];
            __half2 o2  = *(const __half2*)&ow [base + (size_t)tt * CO];
            float2 f  = __half22float2(f2);
            float2 iz = __half22float2(iz2);
            float2 o  = __half22float2(o2);
            cs0 = fmaf(f.x, cs0, iz.x);
            cs1 = fmaf(f.y, cs1, iz.y);
            hbuf[tt][c2]     = o.x * cs0;
            hbuf[tt][c2 + 1] = o.y * cs1;
        }
    }
    __syncthreads();
    int tt = threadIdx.x & 31;
    int cr = threadIdx.x >> 5;
#pragma unroll
    for (int w = 0; w < 32; w++) {
        int cc = cr + w * 8;
        out[((size_t)(b * CO + cc)) * T_ + ch * CL + tt] = hbuf[tt][cc];
    }
}

extern "C" void kernel_launch(void* const* d_in, const int* in_sizes, int n_in,
                              void* d_out, int out_size, void* d_ws, size_t ws_size,
                              hipStream_t stream) {
    const float* x    = (const float*)d_in[0];
    const float* W    = (const float*)d_in[1];
    const float* bias = (const float*)d_in[2];
    float* out = (float*)d_out;
    float* ws  = (float*)d_ws;

    unsigned short* Xhi = (unsigned short*)(ws + OFF_XHI);
    unsigned short* Xlo = (unsigned short*)(ws + OFF_XLO);
    unsigned short* Whi = (unsigned short*)(ws + OFF_WHI);
    unsigned short* Wlo = (unsigned short*)(ws + OFF_WLO);
    __half* fw  = (__half*)(ws + OFF_F16);
    __half* izw = (__half*)(ws + OFF_IZ16);
    __half* ow  = (__half*)(ws + OFF_O16);
    float* Aw  = ws + OFF_A;
    float* Bw  = ws + OFF_B;

    convert_kernel<<<4096, 256, 0, stream>>>(W, x, Whi, Wlo, Xhi, Xlo);
    gemm_mfma_kernel<<<(NN / 128) * (O4 / 128), 512, 0, stream>>>(
        Xhi, Xlo, Whi, Wlo, bias, fw, izw, ow, Aw, Bw);
    scan_phase3<<<dim3(NCH, B_), CO, 0, stream>>>(fw, izw, ow, Aw, Bw, out);
}

// Round 11
// 212.785 us; speedup vs baseline: 1.0322x; 1.0127x over previous
//
#include <hip/hip_runtime.h>
#include <hip/hip_fp16.h>

#define B_   8
#define CIN  256
#define T_   4096
#define TP   4097    // padded T (row 0 = zeros, row t+1 = x[t])
#define CO   256
#define O4   1024
#define NN   32768   // B_*T_
#define NCH  128     // chunks along T
#define CL   32      // chunk length

// ws layout (float offsets)
#define OFF_XHI  0           // ushort [8][4097][256]
#define OFF_XLO  4195328
#define OFF_WHI  8390656     // ushort [1024][512]
#define OFF_WLO  8652800
#define OFF_F16  8914944     // ushort(f16) [8][4096][256]
#define OFF_IZ16 13109248
#define OFF_O16  17303552
#define OFF_A    21497856    // float [8][128][256]
#define OFF_B    21760000

typedef __attribute__((ext_vector_type(8))) short short8;
typedef __attribute__((ext_vector_type(4))) float floatx4;

__device__ __forceinline__ float fsig(float x)  { return 1.0f / (1.0f + __expf(-x)); }
__device__ __forceinline__ float ftanh(float x) { return 2.0f / (1.0f + __expf(-2.0f * x)) - 1.0f; }

__device__ __forceinline__ unsigned short bf16_rne(float v) {
    unsigned u = __float_as_uint(v);
    unsigned r = (u + 0x7fffu + ((u >> 16) & 1u)) >> 16;
    return (unsigned short)r;
}
__device__ __forceinline__ void split_bf16(float v, unsigned short& hi, unsigned short& lo) {
    hi = bf16_rne(v);
    float hf = __uint_as_float(((unsigned)hi) << 16);
    lo = bf16_rne(v - hf);
}

// async 16B/lane global->LDS DMA; lds base must be wave-uniform (dest = base + lane*16)
__device__ __forceinline__ void glds16(const unsigned short* g, unsigned short* l) {
    __builtin_amdgcn_global_load_lds(
        (const __attribute__((address_space(1))) unsigned*)g,
        (__attribute__((address_space(3))) unsigned*)l, 16, 0, 0);
}

// merged converts: bid<2048 -> W repack/split; bid>=2048 -> X transpose/split.
// W[o=g*256+c][i][j] -> Wa[r=c*4+g][k=j*256+i].  x[b][c][t] -> Xpad[b][t+1][c].
__global__ void convert_kernel(const float* __restrict__ W,
                               const float* __restrict__ x,
                               unsigned short* __restrict__ Whi,
                               unsigned short* __restrict__ Wlo,
                               unsigned short* __restrict__ Xhi,
                               unsigned short* __restrict__ Xlo) {
    __shared__ float tile[64][69];      // 69 mod 32 = 5 -> conflict-free both phases
    const int bid = blockIdx.x;
    const int tid = threadIdx.x;
    if (bid < 2048) {
        int e = bid * 256 + tid;        // 1024*512 elements
        int r = e >> 9, k = e & 511;
        int g = r & 3, c = r >> 2;
        int j = k >> 8, i = k & 255;
        float v = W[((size_t)((g << 8) + c)) * 512 + i * 2 + j];
        unsigned short hi, lo;
        split_bf16(v, hi, lo);
        Whi[e] = hi;
        Wlo[e] = lo;
        return;
    }
    const int b2 = bid - 2048;
    const int t0 = (b2 & 63) * 64;
    const int c0 = ((b2 >> 6) & 3) * 64;
    const int b  = b2 >> 8;

    {   // read: float4 along t, 16 rows per pass
        int j4 = (tid & 15) * 4, r16 = tid >> 4;
#pragma unroll
        for (int p = 0; p < 4; p++) {
            int i = p * 16 + r16;
            float4 v = *(const float4*)&x[((size_t)(b * 256 + c0 + i)) * T_ + t0 + j4];
            tile[i][j4] = v.x; tile[i][j4 + 1] = v.y;
            tile[i][j4 + 2] = v.z; tile[i][j4 + 3] = v.w;
        }
    }
    if (t0 == 0 && tid < 64) {   // zero pad row (x[-1] = 0)
        size_t z = (size_t)b * TP * 256 + c0 + tid;
        Xhi[z] = 0; Xlo[z] = 0;
    }
    __syncthreads();
    {   // write: 4 consecutive channels per thread, packed uint2 (8B) stores
        const int cslot = tid & 15, trow = tid >> 4;
#pragma unroll
        for (int p = 0; p < 4; p++) {
            int t = p * 16 + trow;
            unsigned hi0, hi1, lo0, lo1;
            {
                unsigned short h, l;
                split_bf16(tile[cslot * 4 + 0][t], h, l);
                hi0 = h; lo0 = l;
                split_bf16(tile[cslot * 4 + 1][t], h, l);
                hi0 |= ((unsigned)h) << 16; lo0 |= ((unsigned)l) << 16;
                split_bf16(tile[cslot * 4 + 2][t], h, l);
                hi1 = h; lo1 = l;
                split_bf16(tile[cslot * 4 + 3][t], h, l);
                hi1 |= ((unsigned)h) << 16; lo1 |= ((unsigned)l) << 16;
            }
            size_t idx = ((size_t)b * TP + t0 + t + 1) * 256 + c0 + cslot * 4;
            uint2 ph; ph.x = hi0; ph.y = hi1;
            uint2 pl; pl.x = lo0; pl.y = lo1;
            *(uint2*)&Xhi[idx] = ph;
            *(uint2*)&Xlo[idx] = pl;
        }
    }
}

// C[r=1024][n=32768] = Wa · Xb^T, split-bf16 MFMA (3 products).
// Round 11: m201-style fine-phase schedule. 256x256 tile, 8 waves (2M x 4N,
// 128x64 each), BK=32, 16 K-steps, 128 KiB LDS (full 4-plane double buffer).
// SIX phases per K-step (3 products x 2 m-halves), each = {ds_read subtile |
// issue 2 DMA | barrier | lgkmcnt(0)+sched_barrier | setprio(1) 16 MFMA
// setprio(0) | barrier} — the m196-isolated interleave lever. Counted vmcnt
// ONLY at end-ph1 and end-ph5 (both vmcnt(4)); never below 4 in flight.
// FIFO ledger (issues AH'@ph0 BH'@ph1 AL'@ph2 BL'@ph3; consumes AH,BH@ph0/1,
// BL@ph2, AL@ph4/5): steady-state verified; prologue {AH,BH,AL,BL} vmcnt(4).
// Overwrite hazards: every plane's overwrite is >=2 barriers after its last
// reader (AH:ph0/1 vs ph0(i+1); BH:ph0 vs ph1(i+1); BL:ph2 vs ph3(i+1);
// AL:ph4/5 vs ph2(i+1)). XOR swizzle both sides (R7-proven). Product order
// per acc stays hh,hl,lh -> numerics identical. Grid map = R1/R2 (FETCH 33MB).
// Planes (ushort idx, buf d at d*32768): AH+0, AL+8192, BH+16384, BL+24576.
__launch_bounds__(512, 2)
__global__ void gemm_mfma_kernel(const unsigned short* __restrict__ Xhi,
                                 const unsigned short* __restrict__ Xlo,
                                 const unsigned short* __restrict__ Whi,
                                 const unsigned short* __restrict__ Wlo,
                                 const float* __restrict__ bias,
                                 __half* __restrict__ fw,
                                 __half* __restrict__ izw,
                                 __half* __restrict__ ow,
                                 float* __restrict__ Aw,
                                 float* __restrict__ Bw)
{
    __shared__ unsigned short smem_us[65536];   // 128 KiB

    const int tid  = threadIdx.x;
    const int wave = tid >> 6, lane = tid & 63;
    const int q = lane >> 4, mr = lane & 15;
    const int wm = wave >> 2, wn = wave & 3;     // 2 x 4 wave grid (M x N)

    // grid: 512 = 8 xcd x (16 n-tiles x 4 r, r fastest); FETCH=33MB proven
    const int bid   = blockIdx.x;
    const int xcd   = bid & 7;
    const int idx   = bid >> 3;                  // 0..63
    const int n_blk = xcd * 16 + (idx >> 2);     // 0..127
    const int r_blk = idx & 3;                   // 0..3
    const int r0 = r_blk * 256;
    const int n0 = n_blk * 256;
    const int bb = n0 >> 12;
    const int t0 = n0 & (T_ - 1);

    // staging: wave w stages rows w*32 + {0..15,16..31}; 2 DMAs per plane.
    // XOR-swizzled source slice (within each row's contiguous 64B window).
    const int lrow = lane >> 2;                              // 0..15
    const int lcol = (((lane & 3) ^ ((lrow >> 1) & 3)) * 8); // swizzled ushort offset
    const size_t wAoff = (size_t)(r0 + wave * 32 + lrow) * 512 + lcol;
    const unsigned short* pWh0 = Whi + wAoff;
    const unsigned short* pWh1 = pWh0 + 16 * 512;
    const unsigned short* pWl0 = Wlo + wAoff;
    const unsigned short* pWl1 = pWl0 + 16 * 512;
    const size_t xBoff = ((size_t)bb * TP + t0 + wave * 32 + lrow) * 256 + lcol;
    const unsigned short* pXh0 = Xhi + xBoff;
    const unsigned short* pXh1 = pXh0 + 16 * 256;
    const unsigned short* pXl0 = Xlo + xBoff;
    const unsigned short* pXl1 = pXl0 + 16 * 256;

    // fragment read bases (swizzled slice); row bases 16-aligned => same phase
    const int swz = (q ^ ((mr >> 1) & 3)) * 8;
    const int aoffb = (wm * 128 + mr) * 32 + swz;  // + v*512, v=0..7
    const int boffb = (wn * 64  + mr) * 32 + swz;  // + u*512, u=0..3
    const int wst = wave * 1024;                   // wave staging offset in plane

    floatx4 acc[8][4];
#pragma unroll
    for (int v = 0; v < 8; v++)
#pragma unroll
        for (int u = 0; u < 4; u++) acc[v][u] = (floatx4){0.f, 0.f, 0.f, 0.f};

    // prologue: stage K-step 0 into buf0, FIFO order AH,BH,AL,BL
    glds16(pWh0, smem_us + wst);            glds16(pWh1, smem_us + wst + 512);
    glds16(pXh0, smem_us + 16384 + wst);    glds16(pXh1, smem_us + 16384 + wst + 512);
    glds16(pWl0, smem_us + 8192 + wst);     glds16(pWl1, smem_us + 8192 + wst + 512);
    glds16(pXl0, smem_us + 24576 + wst);    glds16(pXl1, smem_us + 24576 + wst + 512);
    asm volatile("s_waitcnt vmcnt(4)" ::: "memory");   // AH,BH landed; AL,BL in flight
    __builtin_amdgcn_s_barrier();
    __builtin_amdgcn_sched_barrier(0);

#pragma unroll 2
    for (int i = 0; i < 16; ++i) {
        const int cur = i & 1, nxt = cur ^ 1;
        const unsigned kkn = (unsigned)(((i + 1) & 15) * 32);  // wrap keeps counts uniform
        const unsigned short* AHc = smem_us + cur * 32768;
        const unsigned short* ALc = AHc + 8192;
        const unsigned short* BHc = AHc + 16384;
        const unsigned short* BLc = AHc + 24576;
        unsigned short* dAH = smem_us + nxt * 32768 + wst;
        unsigned short* dAL = dAH + 8192;
        unsigned short* dBH = dAH + 16384;
        unsigned short* dBL = dAH + 24576;

        short8 ah0[4], ah1[4], bh[4];

        // ===== ph0: hh, m0-3 =====
#pragma unroll
        for (int u = 0; u < 4; ++u) bh[u] = *(const short8*)(BHc + boffb + u * 512);
#pragma unroll
        for (int v = 0; v < 4; ++v) ah0[v] = *(const short8*)(AHc + aoffb + v * 512);
        glds16(pWh0 + kkn, dAH); glds16(pWh1 + kkn, dAH + 512);
        __builtin_amdgcn_s_barrier();
        asm volatile("s_waitcnt lgkmcnt(0)" ::: "memory");
        __builtin_amdgcn_sched_barrier(0);
        __builtin_amdgcn_s_setprio(1);
#pragma unroll
        for (int v = 0; v < 4; ++v)
#pragma unroll
            for (int u = 0; u < 4; ++u)
                acc[v][u] = __builtin_amdgcn_mfma_f32_16x16x32_bf16(ah0[v], bh[u], acc[v][u], 0, 0, 0);
        __builtin_amdgcn_s_setprio(0);
        __builtin_amdgcn_s_barrier();

        // ===== ph1: hh, m4-7 =====
#pragma unroll
        for (int v = 0; v < 4; ++v) ah1[v] = *(const short8*)(AHc + aoffb + (4 + v) * 512);
        glds16(pXh0 + kkn, dBH); glds16(pXh1 + kkn, dBH + 512);
        asm volatile("s_waitcnt vmcnt(4)" ::: "memory");   // BL(i) (and AL(i)) landed
        __builtin_amdgcn_s_barrier();
        asm volatile("s_waitcnt lgkmcnt(0)" ::: "memory");
        __builtin_amdgcn_sched_barrier(0);
        __builtin_amdgcn_s_setprio(1);
#pragma unroll
        for (int v = 0; v < 4; ++v)
#pragma unroll
            for (int u = 0; u < 4; ++u)
                acc[4 + v][u] = __builtin_amdgcn_mfma_f32_16x16x32_bf16(ah1[v], bh[u], acc[4 + v][u], 0, 0, 0);
        __builtin_amdgcn_s_setprio(0);
        __builtin_amdgcn_s_barrier();

        // ===== ph2: hl, m0-3 =====
        {
            short8 bl[4];
#pragma unroll
            for (int u = 0; u < 4; ++u) bl[u] = *(const short8*)(BLc + boffb + u * 512);
            glds16(pWl0 + kkn, dAL); glds16(pWl1 + kkn, dAL + 512);
            __builtin_amdgcn_s_barrier();
            asm volatile("s_waitcnt lgkmcnt(0)" ::: "memory");
            __builtin_amdgcn_sched_barrier(0);
            __builtin_amdgcn_s_setprio(1);
#pragma unroll
            for (int v = 0; v < 4; ++v)
#pragma unroll
                for (int u = 0; u < 4; ++u)
                    acc[v][u] = __builtin_amdgcn_mfma_f32_16x16x32_bf16(ah0[v], bl[u], acc[v][u], 0, 0, 0);
            __builtin_amdgcn_s_setprio(0);
            __builtin_amdgcn_s_barrier();

            // ===== ph3: hl, m4-7 (bl, ah1 in regs; no ds reads) =====
            glds16(pXl0 + kkn, dBL); glds16(pXl1 + kkn, dBL + 512);
            __builtin_amdgcn_s_barrier();
            __builtin_amdgcn_sched_barrier(0);
            __builtin_amdgcn_s_setprio(1);
#pragma unroll
            for (int v = 0; v < 4; ++v)
#pragma unroll
                for (int u = 0; u < 4; ++u)
                    acc[4 + v][u] = __builtin_amdgcn_mfma_f32_16x16x32_bf16(ah1[v], bl[u], acc[4 + v][u], 0, 0, 0);
            __builtin_amdgcn_s_setprio(0);
            __builtin_amdgcn_s_barrier();
        }

        // ===== ph4: lh, m0-3 =====
        {
            short8 al[4];
#pragma unroll
            for (int v = 0; v < 4; ++v) al[v] = *(const short8*)(ALc + aoffb + v * 512);
            __builtin_amdgcn_s_barrier();
            asm volatile("s_waitcnt lgkmcnt(0)" ::: "memory");
            __builtin_amdgcn_sched_barrier(0);
            __builtin_amdgcn_s_setprio(1);
#pragma unroll
            for (int v = 0; v < 4; ++v)
#pragma unroll
                for (int u = 0; u < 4; ++u)
                    acc[v][u] = __builtin_amdgcn_mfma_f32_16x16x32_bf16(al[v], bh[u], acc[v][u], 0, 0, 0);
            __builtin_amdgcn_s_setprio(0);
            __builtin_amdgcn_s_barrier();
        }

        // ===== ph5: lh, m4-7 =====
        {
            short8 al[4];
#pragma unroll
            for (int v = 0; v < 4; ++v) al[v] = *(const short8*)(ALc + aoffb + (4 + v) * 512);
            asm volatile("s_waitcnt vmcnt(4)" ::: "memory");   // AH',BH' landed
            __builtin_amdgcn_s_barrier();
            asm volatile("s_waitcnt lgkmcnt(0)" ::: "memory");
            __builtin_amdgcn_sched_barrier(0);
            __builtin_amdgcn_s_setprio(1);
#pragma unroll
            for (int v = 0; v < 4; ++v)
#pragma unroll
                for (int u = 0; u < 4; ++u)
                    acc[4 + v][u] = __builtin_amdgcn_mfma_f32_16x16x32_bf16(al[v], bh[u], acc[4 + v][u], 0, 0, 0);
            __builtin_amdgcn_s_setprio(0);
            __builtin_amdgcn_s_barrier();
        }
    }

    // ---------- epilogue ----------
    asm volatile("s_waitcnt vmcnt(0)" ::: "memory");   // drain wrap-staging junk DMAs
    __syncthreads();                     // LDS reused below
    __half* epf = (__half*)smem_us;      // [256][72] f16
    __half* epz = epf + 256 * 72;
    __half* epo = epz + 256 * 72;        // total 110,592 B < 128 KiB
    const int ch_base = r0 >> 2;         // 64 channels per block

#pragma unroll
    for (int v = 0; v < 8; ++v) {
        const int cl = wm * 32 + v * 4 + q;          // local channel 0..63
        const int ch = ch_base + cl;
        const float bz  = bias[ch];
        const float bf_ = bias[256 + ch];
        const float bo  = bias[512 + ch];
        const float bi  = bias[768 + ch];
#pragma unroll
        for (int u = 0; u < 4; ++u) {
            const int t_l = wn * 64 + u * 16 + mr;   // local t 0..255
            float zv = ftanh(acc[v][u][0] + bz);
            float fv = fsig(acc[v][u][1] + bf_);
            float ov = fsig(acc[v][u][2] + bo);
            float iv = fsig(acc[v][u][3] + bi);
            const int off = t_l * 72 + cl;
            epf[off] = __float2half(fv);             // same f16 rounding as before
            epz[off] = __float2half(iv * zv);
            epo[off] = __float2half(ov);
        }
    }
    __syncthreads();

    // coalesced f16 stores: 2 threads per t-row, 32 channels (4x uint4) each
    {
        const int t_r = tid >> 1;                    // 0..255
        const int cb = (tid & 1) << 5;               // 0 or 32
        const size_t gbase = ((size_t)bb * T_ + t0 + t_r) * 256 + ch_base + cb;
        const int lb = t_r * 72 + cb;                // 16B-aligned (144 | 16)
        {
            const uint4* s = (const uint4*)&epf[lb];
            uint4* d = (uint4*)&fw[gbase];
            d[0] = s[0]; d[1] = s[1]; d[2] = s[2]; d[3] = s[3];
        }
        {
            const uint4* s = (const uint4*)&epz[lb];
            uint4* d = (uint4*)&izw[gbase];
            d[0] = s[0]; d[1] = s[1]; d[2] = s[2]; d[3] = s[3];
        }
        {
            const uint4* s = (const uint4*)&epo[lb];
            uint4* d = (uint4*)&ow[gbase];
            d[0] = s[0]; d[1] = s[1]; d[2] = s[2]; d[3] = s[3];
        }
    }

    // fused scan phase 1: per-chunk (A = prod f, B = affine end); 8 chunks x 64 ch
    {
        const int chunk = tid >> 6;                  // 0..7 (== wave)
        const int c = tid & 63;
        float A = 1.0f, Bv = 0.0f;
        const int base = (chunk * 32) * 72 + c;
#pragma unroll 4
        for (int j = 0; j < 32; ++j) {
            float f  = __half2float(epf[base + j * 72]);
            float iz = __half2float(epz[base + j * 72]);
            Bv = fmaf(f, Bv, iz);
            A *= f;
        }
        const int chunk_abs = (t0 >> 5) + chunk;
        const size_t aidx = ((size_t)bb * NCH + chunk_abs) * 256 + ch_base + c;
        Aw[aidx] = A;
        Bw[aidx] = Bv;
    }
}

// Phase 3 (merged with old phase 2): each block computes its own carry from
// the chunk summaries (predicated 16-wide batched loads; Aw/Bw are L2-hot
// 256KB), then replays the recurrence and writes out[b][c][t] transposed.
__global__ void scan_phase3(const __half* __restrict__ fw, const __half* __restrict__ izw,
                            const __half* __restrict__ ow,
                            const float* __restrict__ Aw, const float* __restrict__ Bw,
                            float* __restrict__ out)
{
    __shared__ float hbuf[CL][257];
    __shared__ float carry_s[256];
    int b = blockIdx.y, ch = blockIdx.x;
    int tid = threadIdx.x;

    {   // carry over chunks 0..ch-1 for channel tid (exclusive scan, batched)
        const int c = tid;
        float carry = 0.0f;
        for (int g = 0; g < 8; ++g) {
            if (g * 16 >= ch) break;
            float Ar[16], Br[16];
#pragma unroll
            for (int j = 0; j < 16; ++j) {
                int jj = g * 16 + j;
                bool ok = jj < ch;
                size_t idx2 = ((size_t)(b * NCH + (ok ? jj : 0))) * CO + c;
                Ar[j] = ok ? Aw[idx2] : 1.0f;
                Br[j] = ok ? Bw[idx2] : 0.0f;
            }
#pragma unroll
            for (int j = 0; j < 16; ++j) carry = fmaf(Ar[j], carry, Br[j]);
        }
        carry_s[c] = carry;
    }
    __syncthreads();

    if (tid < 128) {
        const int c2 = tid * 2;
        float cs0 = carry_s[c2];
        float cs1 = carry_s[c2 + 1];
        size_t base = ((size_t)(b * T_ + ch * CL)) * CO + c2;
#pragma unroll 4
        for (int tt = 0; tt < CL; tt++) {
            __half2 f2  = *(const __half2*)&fw [base + (size_t)tt * CO];
            __half2 iz2 = *(const __half2*)&izw[base + (size_t)tt * CO];
            __half2 o2  = *(const __half2*)&ow [base + (size_t)tt * CO];
            float2 f  = __half22float2(f2);
            float2 iz = __half22float2(iz2);
            float2 o  = __half22float2(o2);
            cs0 = fmaf(f.x, cs0, iz.x);
            cs1 = fmaf(f.y, cs1, iz.y);
            hbuf[tt][c2]     = o.x * cs0;
            hbuf[tt][c2 + 1] = o.y * cs1;
        }
    }
    __syncthreads();
    int tt = threadIdx.x & 31;
    int cr = threadIdx.x >> 5;
#pragma unroll
    for (int w = 0; w < 32; w++) {
        int cc = cr + w * 8;
        out[((size_t)(b * CO + cc)) * T_ + ch * CL + tt] = hbuf[tt][cc];
    }
}

extern "C" void kernel_launch(void* const* d_in, const int* in_sizes, int n_in,
                              void* d_out, int out_size, void* d_ws, size_t ws_size,
                              hipStream_t stream) {
    const float* x    = (const float*)d_in[0];
    const float* W    = (const float*)d_in[1];
    const float* bias = (const float*)d_in[2];
    float* out = (float*)d_out;
    float* ws  = (float*)d_ws;

    unsigned short* Xhi = (unsigned short*)(ws + OFF_XHI);
    unsigned short* Xlo = (unsigned short*)(ws + OFF_XLO);
    unsigned short* Whi = (unsigned short*)(ws + OFF_WHI);
    unsigned short* Wlo = (unsigned short*)(ws + OFF_WLO);
    __half* fw  = (__half*)(ws + OFF_F16);
    __half* izw = (__half*)(ws + OFF_IZ16);
    __half* ow  = (__half*)(ws + OFF_O16);
    float* Aw  = ws + OFF_A;
    float* Bw  = ws + OFF_B;

    convert_kernel<<<4096, 256, 0, stream>>>(W, x, Whi, Wlo, Xhi, Xlo);
    gemm_mfma_kernel<<<(NN / 256) * (O4 / 256), 512, 0, stream>>>(
        Xhi, Xlo, Whi, Wlo, bias, fw, izw, ow, Aw, Bw);
    scan_phase3<<<dim3(NCH, B_), CO, 0, stream>>>(fw, izw, ow, Aw, Bw, out);
}

// Round 13
// 155.265 us; speedup vs baseline: 1.4146x; 1.3705x over previous
//
#include <hip/hip_runtime.h>
#include <hip/hip_fp16.h>

#define B_   8
#define CIN  256
#define T_   4096
#define TP   4097    // padded T (row 0 = zeros, row t+1 = x[t])
#define CO   256
#define O4   1024
#define NN   32768   // B_*T_
#define NCH  128     // chunks along T
#define CL   32      // chunk length

// ws layout (float offsets) — f16 single-precision pipeline (70 MB total)
#define OFF_XF   0            // half [8][4097][256]
#define OFF_WF   4195328      // half [1024][512]
#define OFF_F16  4457472      // half [8][4096][256]
#define OFF_IZ16 8651776
#define OFF_O16  12846080
#define OFF_A    17040384     // float [8][128][256]
#define OFF_B    17302528

typedef __attribute__((ext_vector_type(8))) _Float16 half8;
typedef __attribute__((ext_vector_type(4))) float floatx4;

__device__ __forceinline__ float fsig(float x)  { return 1.0f / (1.0f + __expf(-x)); }
__device__ __forceinline__ float ftanh(float x) { return 2.0f / (1.0f + __expf(-2.0f * x)) - 1.0f; }

__device__ __forceinline__ unsigned short f16b(float v) {
    return __half_as_ushort(__float2half(v));
}

// async 16B/lane global->LDS DMA; lds base must be wave-uniform (dest = base + lane*16)
__device__ __forceinline__ void glds16(const unsigned short* g, unsigned short* l) {
    __builtin_amdgcn_global_load_lds(
        (const __attribute__((address_space(1))) unsigned*)g,
        (__attribute__((address_space(3))) unsigned*)l, 16, 0, 0);
}

// merged converts: bid<2048 -> W repack to f16; bid>=2048 -> X transpose to f16.
// W[o=g*256+c][i][j] -> Wf[r=c*4+g][k=j*256+i].  x[b][c][t] -> Xf[b][t+1][c].
__global__ void convert_kernel(const float* __restrict__ W,
                               const float* __restrict__ x,
                               unsigned short* __restrict__ Wf,
                               unsigned short* __restrict__ Xf) {
    __shared__ float tile[64][69];      // 69 mod 32 = 5 -> conflict-free both phases
    const int bid = blockIdx.x;
    const int tid = threadIdx.x;
    if (bid < 2048) {
        int e = bid * 256 + tid;        // 1024*512 elements
        int r = e >> 9, k = e & 511;
        int g = r & 3, c = r >> 2;
        int j = k >> 8, i = k & 255;
        float v = W[((size_t)((g << 8) + c)) * 512 + i * 2 + j];
        Wf[e] = f16b(v);
        return;
    }
    const int b2 = bid - 2048;
    const int t0 = (b2 & 63) * 64;
    const int c0 = ((b2 >> 6) & 3) * 64;
    const int b  = b2 >> 8;

    {   // read: float4 along t, 16 rows per pass
        int j4 = (tid & 15) * 4, r16 = tid >> 4;
#pragma unroll
        for (int p = 0; p < 4; p++) {
            int i = p * 16 + r16;
            float4 v = *(const float4*)&x[((size_t)(b * 256 + c0 + i)) * T_ + t0 + j4];
            tile[i][j4] = v.x; tile[i][j4 + 1] = v.y;
            tile[i][j4 + 2] = v.z; tile[i][j4 + 3] = v.w;
        }
    }
    if (t0 == 0 && tid < 64) {   // zero pad row (x[-1] = 0)
        Xf[(size_t)b * TP * 256 + c0 + tid] = 0;
    }
    __syncthreads();
    {   // write: 4 consecutive channels per thread, packed uint2 (8B) stores
        const int cslot = tid & 15, trow = tid >> 4;
#pragma unroll
        for (int p = 0; p < 4; p++) {
            int t = p * 16 + trow;
            unsigned lo = (unsigned)f16b(tile[cslot * 4 + 0][t])
                        | ((unsigned)f16b(tile[cslot * 4 + 1][t]) << 16);
            unsigned hi = (unsigned)f16b(tile[cslot * 4 + 2][t])
                        | ((unsigned)f16b(tile[cslot * 4 + 3][t]) << 16);
            size_t idx = ((size_t)b * TP + t0 + t + 1) * 256 + c0 + cslot * 4;
            uint2 pk; pk.x = lo; pk.y = hi;
            *(uint2*)&Xf[idx] = pk;
        }
    }
}

// C[r=1024][n=32768] = Wf · Xf^T, SINGLE-PRODUCT f16 MFMA.
// Round 13 (= round 12 resubmitted after infra failure; hazard audit clean).
// The 3-product split-bf16 formulation was LDS-read-pipe-bound (96KB
// fragment reads per 128^2 K-step at 85 B/cyc — m134; six schedule variants
// all ~111-122us). f16 inputs cut operand traffic 3x; the added input-
// rounding error (~8e-4 pre-activation) is comparable to the f16 gate
// rounding already in the pipeline (absmax expected ~0.005-0.008).
// Structure: 128x128 tile, 8 waves (2Mx4N, 64x32), BK=32, 16 K-steps,
// TRIPLE-buffered LDS (3 x 16KB = 48KB -> 3 blocks/CU, 24 waves/CU;
// f16 halves the L2 live footprint that thrashed R10's 3-blk attempt).
// Prefetch distance 2; per step: issue pair->buf[(i+2)%3], read frags from
// buf[i%3], lgkm+MFMA, vmcnt(2) [(i+1) pair landed], ONE barrier. Overwrite
// target (i+2)%3 == (i-1)%3, readers done before barrier i-1 => safe.
// XOR swizzle both sides (R7-proven, geometry identical). Grid map = R7
// (FETCH 32MB proven). Buf d (ushort idx): A at d*8192, B at d*8192+4096.
__launch_bounds__(512, 6)
__global__ void gemm_mfma_kernel(const unsigned short* __restrict__ Xf,
                                 const unsigned short* __restrict__ Wf,
                                 const float* __restrict__ bias,
                                 __half* __restrict__ fw,
                                 __half* __restrict__ izw,
                                 __half* __restrict__ ow,
                                 float* __restrict__ Aw,
                                 float* __restrict__ Bw)
{
    __shared__ unsigned short smem_us[24576];   // 48 KiB

    const int tid  = threadIdx.x;
    const int wave = tid >> 6, lane = tid & 63;
    const int q = lane >> 4, mr = lane & 15;
    const int wm = wave >> 2, wn = wave & 3;     // 2 x 4 wave grid (M x N)

    // grid: 2048 = 8 xcd x (32 n-tiles x 8 r, r fastest -> X-tile L2-resident)
    const int bid   = blockIdx.x;
    const int xcd   = bid & 7;
    const int idx   = bid >> 3;                  // 0..255
    const int n_blk = xcd * 32 + (idx >> 3);     // 0..255
    const int r_blk = idx & 7;                   // 0..7
    const int r0 = r_blk * 128;
    const int n0 = n_blk * 128;
    const int bb = n0 >> 12;
    const int t0 = n0 & (T_ - 1);

    // staging: wave w stages rows w*16..w*16+15 of A and B; 1 DMA per plane.
    // XOR-swizzled source slice (within the row's contiguous 64B K-window).
    const int lrow = lane >> 2;                              // 0..15
    const int lcol = (((lane & 3) ^ ((lrow >> 1) & 3)) * 8); // swizzled ushort offset
    const unsigned short* pW = Wf + (size_t)(r0 + wave * 16 + lrow) * 512 + lcol;
    const unsigned short* pX = Xf + ((size_t)bb * TP + t0 + wave * 16 + lrow) * 256 + lcol;

    // fragment read bases (ushort offsets within one plane, swizzled slice)
    const int swz = (q ^ ((mr >> 1) & 3)) * 8;
    const int aoffb = (wm * 64 + mr) * 32 + swz;   // + v*512, v=0..3
    const int boffb = (wn * 32 + mr) * 32 + swz;   // + u*512, u=0..1
    const int wst = wave * 512;                  // wave staging offset in plane

    floatx4 acc[4][2];
#pragma unroll
    for (int v = 0; v < 4; v++)
#pragma unroll
        for (int u = 0; u < 2; u++) acc[v][u] = (floatx4){0.f, 0.f, 0.f, 0.f};

    // prologue: k0 -> buf0, k1 -> buf1 (pairs in FIFO order A,B)
    glds16(pW,      smem_us + wst);
    glds16(pX,      smem_us + 4096 + wst);
    glds16(pW + 32, smem_us + 8192 + wst);
    glds16(pX + 32, smem_us + 8192 + 4096 + wst);
    asm volatile("s_waitcnt vmcnt(2)" ::: "memory");   // k0 pair landed
    __builtin_amdgcn_s_barrier();
    __builtin_amdgcn_sched_barrier(0);

#pragma unroll 16
    for (int i = 0; i < 16; ++i) {
        const unsigned short* Ac = smem_us + (i % 3) * 8192;
        const unsigned short* Bc = Ac + 4096;
        unsigned short* dA = smem_us + ((i + 2) % 3) * 8192 + wst;
        unsigned short* dB = dA + 4096;
        const unsigned kkn = (unsigned)(((i + 2) & 15) * 32);  // wrap keeps counts uniform

        // issue next+1 pair early (lands under the next two MFMA phases)
        glds16(pW + kkn, dA);
        glds16(pX + kkn, dB);

        half8 ah[4], bh[2];
#pragma unroll
        for (int v = 0; v < 4; ++v) ah[v] = *(const half8*)(Ac + aoffb + v * 512);
#pragma unroll
        for (int u = 0; u < 2; ++u) bh[u] = *(const half8*)(Bc + boffb + u * 512);
        asm volatile("s_waitcnt lgkmcnt(0)" ::: "memory");
        __builtin_amdgcn_sched_barrier(0);
        __builtin_amdgcn_s_setprio(1);
#pragma unroll
        for (int v = 0; v < 4; ++v)
#pragma unroll
            for (int u = 0; u < 2; ++u)
                acc[v][u] = __builtin_amdgcn_mfma_f32_16x16x32_f16(ah[v], bh[u], acc[v][u], 0, 0, 0);
        __builtin_amdgcn_s_setprio(0);
        asm volatile("s_waitcnt vmcnt(2)" ::: "memory");   // (i+1) pair landed
        __builtin_amdgcn_s_barrier();
        __builtin_amdgcn_sched_barrier(0);
    }

    // ---------- epilogue ----------
    asm volatile("s_waitcnt vmcnt(0)" ::: "memory");   // drain wrap-staging junk DMAs
    __syncthreads();                     // LDS reused below
    __half* epf = (__half*)smem_us;      // [128][36] f16, 72B rows (conflict-free t-phase)
    __half* epz = epf + 128 * 36;
    __half* epo = epz + 128 * 36;        // total 27,648 B < 48 KiB
    const int ch_base = r0 >> 2;         // 32 channels per block

#pragma unroll
    for (int v = 0; v < 4; ++v) {
        const int cl = wm * 16 + v * 4 + q;          // local channel 0..31
        const int ch = ch_base + cl;
        const float bz  = bias[ch];
        const float bf_ = bias[256 + ch];
        const float bo  = bias[512 + ch];
        const float bi  = bias[768 + ch];
#pragma unroll
        for (int u = 0; u < 2; ++u) {
            const int t_l = wn * 32 + u * 16 + mr;   // local t 0..127
            float zv = ftanh(acc[v][u][0] + bz);
            float fv = fsig(acc[v][u][1] + bf_);
            float ov = fsig(acc[v][u][2] + bo);
            float iv = fsig(acc[v][u][3] + bi);
            const int off = t_l * 36 + cl;
            epf[off] = __float2half(fv);             // same f16 rounding as before
            epz[off] = __float2half(iv * zv);
            epo[off] = __float2half(ov);
        }
    }
    __syncthreads();

    // coalesced f16 stores: 4 threads per t-row, 8 channels (16B) each
    {
        const int t_r = tid >> 2;                    // 0..127
        const int c8 = (tid & 3) << 3;               // 0,8,16,24
        const size_t gbase = ((size_t)bb * T_ + t0 + t_r) * 256 + ch_base + c8;
        const int lb = t_r * 36 + c8;                // 8B-aligned
        union { uint2 u2[2]; uint4 u4; } pk;
        pk.u2[0] = *(const uint2*)&epf[lb];
        pk.u2[1] = *(const uint2*)&epf[lb + 4];
        *(uint4*)&fw[gbase] = pk.u4;
        pk.u2[0] = *(const uint2*)&epz[lb];
        pk.u2[1] = *(const uint2*)&epz[lb + 4];
        *(uint4*)&izw[gbase] = pk.u4;
        pk.u2[0] = *(const uint2*)&epo[lb];
        pk.u2[1] = *(const uint2*)&epo[lb + 4];
        *(uint4*)&ow[gbase] = pk.u4;
    }

    // fused scan phase 1: per-chunk (A = prod f, B = affine end); 4 chunks x 32 ch
    if (tid < 128) {
        const int chunk = tid >> 5;                  // 0..3
        const int c = tid & 31;
        float A = 1.0f, Bv = 0.0f;
        const int base = (chunk * 32) * 36 + c;
#pragma unroll 4
        for (int j = 0; j < 32; ++j) {
            float f  = __half2float(epf[base + j * 36]);
            float iz = __half2float(epz[base + j * 36]);
            Bv = fmaf(f, Bv, iz);
            A *= f;
        }
        const int chunk_abs = (t0 >> 5) + chunk;
        const size_t aidx = ((size_t)bb * NCH + chunk_abs) * 256 + ch_base + c;
        Aw[aidx] = A;
        Bw[aidx] = Bv;
    }
}

// Phase 3: each block computes its own carry from the chunk summaries
// (L2-hot), then replays the recurrence and writes out[b][c][t] transposed
// with float4 stores.
__global__ void scan_phase3(const __half* __restrict__ fw, const __half* __restrict__ izw,
                            const __half* __restrict__ ow,
                            const float* __restrict__ Aw, const float* __restrict__ Bw,
                            float* __restrict__ out)
{
    __shared__ float hbuf[CL][257];
    __shared__ float carry_s[256];
    int b = blockIdx.y, ch = blockIdx.x;
    int tid = threadIdx.x;

    {   // carry over chunks 0..ch-1 for channel tid (exclusive scan, batched)
        const int c = tid;
        float carry = 0.0f;
        for (int g = 0; g < 8; ++g) {
            if (g * 16 >= ch) break;
            float Ar[16], Br[16];
#pragma unroll
            for (int j = 0; j < 16; ++j) {
                int jj = g * 16 + j;
                bool ok = jj < ch;
                size_t idx2 = ((size_t)(b * NCH + (ok ? jj : 0))) * CO + c;
                Ar[j] = ok ? Aw[idx2] : 1.0f;
                Br[j] = ok ? Bw[idx2] : 0.0f;
            }
#pragma unroll
            for (int j = 0; j < 16; ++j) carry = fmaf(Ar[j], carry, Br[j]);
        }
        carry_s[c] = carry;
    }
    __syncthreads();

    if (tid < 128) {
        const int c2 = tid * 2;
        float cs0 = carry_s[c2];
        float cs1 = carry_s[c2 + 1];
        size_t base = ((size_t)(b * T_ + ch * CL)) * CO + c2;
#pragma unroll 4
        for (int tt = 0; tt < CL; tt++) {
            __half2 f2  = *(const __half2*)&fw [base + (size_t)tt * CO];
            __half2 iz2 = *(const __half2*)&izw[base + (size_t)tt * CO];
            __half2 o2  = *(const __half2*)&ow [base + (size_t)tt * CO];
            float2 f  = __half22float2(f2);
            float2 iz = __half22float2(iz2);
            float2 o  = __half22float2(o2);
            cs0 = fmaf(f.x, cs0, iz.x);
            cs1 = fmaf(f.y, cs1, iz.y);
            hbuf[tt][c2]     = o.x * cs0;
            hbuf[tt][c2 + 1] = o.y * cs1;
        }
    }
    __syncthreads();

    // float4 out-stores: thread (tt-group, cc) writes 4 consecutive t
    {
        const int tt4 = (tid & 7) * 4;               // 0,4,...,28
        const int cc0 = tid >> 3;                    // 0..31
#pragma unroll
        for (int w = 0; w < 8; ++w) {
            const int cc = cc0 + w * 32;
            float4 h4;
            h4.x = hbuf[tt4 + 0][cc];
            h4.y = hbuf[tt4 + 1][cc];
            h4.z = hbuf[tt4 + 2][cc];
            h4.w = hbuf[tt4 + 3][cc];
            *(float4*)&out[((size_t)(b * CO + cc)) * T_ + ch * CL + tt4] = h4;
        }
    }
}

extern "C" void kernel_launch(void* const* d_in, const int* in_sizes, int n_in,
                              void* d_out, int out_size, void* d_ws, size_t ws_size,
                              hipStream_t stream) {
    const float* x    = (const float*)d_in[0];
    const float* W    = (const float*)d_in[1];
    const float* bias = (const float*)d_in[2];
    float* out = (float*)d_out;
    float* ws  = (float*)d_ws;

    unsigned short* Xf = (unsigned short*)(ws + OFF_XF);
    unsigned short* Wf = (unsigned short*)(ws + OFF_WF);
    __half* fw  = (__half*)(ws + OFF_F16);
    __half* izw = (__half*)(ws + OFF_IZ16);
    __half* ow  = (__half*)(ws + OFF_O16);
    float* Aw  = ws + OFF_A;
    float* Bw  = ws + OFF_B;

    convert_kernel<<<4096, 256, 0, stream>>>(W, x, Wf, Xf);
    gemm_mfma_kernel<<<(NN / 128) * (O4 / 128), 512, 0, stream>>>(
        Xf, Wf, bias, fw, izw, ow, Aw, Bw);
    scan_phase3<<<dim3(NCH, B_), CO, 0, stream>>>(fw, izw, ow, Aw, Bw, out);
}

// Round 14
// 154.937 us; speedup vs baseline: 1.4176x; 1.0021x over previous
//
#include <hip/hip_runtime.h>
#include <hip/hip_fp16.h>

#define B_   8
#define CIN  256
#define T_   4096
#define TP   4097    // padded T (row 0 = zeros, row t+1 = x[t])
#define CO   256
#define O4   1024
#define NN   32768   // B_*T_
#define NCH  128     // chunks along T
#define CL   32      // chunk length

// ws layout (float offsets) — f16 single-precision pipeline (70 MB total)
#define OFF_XF   0            // half [8][4097][256]
#define OFF_WF   4195328      // half [1024][512]
#define OFF_F16  4457472      // half [8][4096][256]
#define OFF_IZ16 8651776
#define OFF_O16  12846080
#define OFF_A    17040384     // float [8][128][256]
#define OFF_B    17302528

typedef __attribute__((ext_vector_type(8))) _Float16 half8;
typedef __attribute__((ext_vector_type(4))) float floatx4;

__device__ __forceinline__ float fsig(float x)  { return 1.0f / (1.0f + __expf(-x)); }
__device__ __forceinline__ float ftanh(float x) { return 2.0f / (1.0f + __expf(-2.0f * x)) - 1.0f; }

__device__ __forceinline__ unsigned short f16b(float v) {
    return __half_as_ushort(__float2half(v));
}

// async 16B/lane global->LDS DMA; lds base must be wave-uniform (dest = base + lane*16)
__device__ __forceinline__ void glds16(const unsigned short* g, unsigned short* l) {
    __builtin_amdgcn_global_load_lds(
        (const __attribute__((address_space(1))) unsigned*)g,
        (__attribute__((address_space(3))) unsigned*)l, 16, 0, 0);
}

// merged converts: bid<2048 -> W repack to f16; bid>=2048 -> X transpose to f16.
// W[o=g*256+c][i][j] -> Wf[r=c*4+g][k=j*256+i].  x[b][c][t] -> Xf[b][t+1][c].
__global__ void convert_kernel(const float* __restrict__ W,
                               const float* __restrict__ x,
                               unsigned short* __restrict__ Wf,
                               unsigned short* __restrict__ Xf) {
    __shared__ float tile[64][69];      // 69 mod 32 = 5 -> conflict-free both phases
    const int bid = blockIdx.x;
    const int tid = threadIdx.x;
    if (bid < 2048) {
        int e = bid * 256 + tid;        // 1024*512 elements
        int r = e >> 9, k = e & 511;
        int g = r & 3, c = r >> 2;
        int j = k >> 8, i = k & 255;
        float v = W[((size_t)((g << 8) + c)) * 512 + i * 2 + j];
        Wf[e] = f16b(v);
        return;
    }
    const int b2 = bid - 2048;
    const int t0 = (b2 & 63) * 64;
    const int c0 = ((b2 >> 6) & 3) * 64;
    const int b  = b2 >> 8;

    {   // read: float4 along t, 16 rows per pass
        int j4 = (tid & 15) * 4, r16 = tid >> 4;
#pragma unroll
        for (int p = 0; p < 4; p++) {
            int i = p * 16 + r16;
            float4 v = *(const float4*)&x[((size_t)(b * 256 + c0 + i)) * T_ + t0 + j4];
            tile[i][j4] = v.x; tile[i][j4 + 1] = v.y;
            tile[i][j4 + 2] = v.z; tile[i][j4 + 3] = v.w;
        }
    }
    if (t0 == 0 && tid < 64) {   // zero pad row (x[-1] = 0)
        Xf[(size_t)b * TP * 256 + c0 + tid] = 0;
    }
    __syncthreads();
    {   // write: 4 consecutive channels per thread, packed uint2 (8B) stores
        const int cslot = tid & 15, trow = tid >> 4;
#pragma unroll
        for (int p = 0; p < 4; p++) {
            int t = p * 16 + trow;
            unsigned lo = (unsigned)f16b(tile[cslot * 4 + 0][t])
                        | ((unsigned)f16b(tile[cslot * 4 + 1][t]) << 16);
            unsigned hi = (unsigned)f16b(tile[cslot * 4 + 2][t])
                        | ((unsigned)f16b(tile[cslot * 4 + 3][t]) << 16);
            size_t idx = ((size_t)b * TP + t0 + t + 1) * 256 + c0 + cslot * 4;
            uint2 pk; pk.x = lo; pk.y = hi;
            *(uint2*)&Xf[idx] = pk;
        }
    }
}

// C[r=1024][n=32768] = Wf · Xf^T, single-product f16 MFMA.
// Round 14: 256x128 tile, 8 waves (4M x 2N) of 64x64 — R13 was LDS-read-
// pipe-bound (6 reads : 8 MFMA per wave-step => 30.7us read demand vs
// 16.6us MFMA). 64x64 wave tiles: 8 reads : 16 MFMA => 20.5us, balanced.
// f16 halves the per-XCD L2 footprint to ~3MB (<4MiB) — R9's bf16 version
// of this tile thrashed at 6MB; this is the halved-footprint retry.
// Triple-buffered LDS 3 x 24KB = 72KB -> 2 blocks/CU. R13's proven
// schedule: prefetch distance 2, ONE barrier/step, counted vmcnt.
// 3 DMAs/wave/step (A0,A1,B): prologue 6 in flight, vmcnt(3) = k0 landed;
// loop: issue 3 for k(i+2) -> 6 in flight; after MFMA vmcnt(3) = k(i+1)
// landed. Overwrite target (i+2)%3 == (i-1)%3, readers done => safe.
// XOR swizzle both sides (row geometry identical to R7/R13).
// Buf d (ushort idx): A at d*12288 (16KB), B at d*12288+8192 (8KB).
// Epilogue = R9's refcheck-proven 64-channel mapping.
__launch_bounds__(512, 4)
__global__ void gemm_mfma_kernel(const unsigned short* __restrict__ Xf,
                                 const unsigned short* __restrict__ Wf,
                                 const float* __restrict__ bias,
                                 __half* __restrict__ fw,
                                 __half* __restrict__ izw,
                                 __half* __restrict__ ow,
                                 float* __restrict__ Aw,
                                 float* __restrict__ Bw)
{
    __shared__ unsigned short smem_us[36864];   // 72 KiB

    const int tid  = threadIdx.x;
    const int wave = tid >> 6, lane = tid & 63;
    const int q = lane >> 4, mr = lane & 15;
    const int wm = wave >> 1, wn = wave & 1;     // 4 x 2 wave grid (M x N)

    // grid: 1024 = 8 xcd x (32 n-tiles x 4 r, r fastest -> X-tile L2-resident)
    const int bid   = blockIdx.x;
    const int xcd   = bid & 7;
    const int idx   = bid >> 3;                  // 0..127
    const int n_blk = xcd * 32 + (idx >> 2);     // 0..255
    const int r_blk = idx & 3;                   // 0..3
    const int r0 = r_blk * 256;
    const int n0 = n_blk * 128;
    const int bb = n0 >> 12;
    const int t0 = n0 & (T_ - 1);

    // staging: XOR-swizzled source slice within each row's contiguous 64B.
    const int lrow = lane >> 2;                              // 0..15
    const int lcol = (((lane & 3) ^ ((lrow >> 1) & 3)) * 8); // swizzled ushort offset
    // A: wave stages rows wave*32 + lrow + {0,16}: 2 DMAs
    const unsigned short* pW0 = Wf + (size_t)(r0 + wave * 32 + lrow) * 512 + lcol;
    const unsigned short* pW1 = pW0 + 16 * 512;
    // B: wave stages rows wave*16 + lrow: 1 DMA
    const unsigned short* pX = Xf + ((size_t)bb * TP + t0 + wave * 16 + lrow) * 256 + lcol;

    // fragment read bases (ushort offsets within one buffer, swizzled slice)
    const int swz = (q ^ ((mr >> 1) & 3)) * 8;
    const int aoffb = (wm * 64 + mr) * 32 + swz;          // + v*512, v=0..3
    const int boffb = 8192 + (wn * 64 + mr) * 32 + swz;   // + u*512, u=0..3
    const int wstA = wave * 1024;                // wave offset in A plane
    const int wstB = 8192 + wave * 512;          // wave offset in B plane

    floatx4 acc[4][4];
#pragma unroll
    for (int v = 0; v < 4; v++)
#pragma unroll
        for (int u = 0; u < 4; u++) acc[v][u] = (floatx4){0.f, 0.f, 0.f, 0.f};

    // prologue: k0 -> buf0, k1 -> buf1 (per-wave FIFO order A0,A1,B)
    glds16(pW0,      smem_us + wstA);
    glds16(pW1,      smem_us + wstA + 512);
    glds16(pX,       smem_us + wstB);
    glds16(pW0 + 32, smem_us + 12288 + wstA);
    glds16(pW1 + 32, smem_us + 12288 + wstA + 512);
    glds16(pX + 32,  smem_us + 12288 + wstB);
    asm volatile("s_waitcnt vmcnt(3)" ::: "memory");   // k0 triple landed
    __builtin_amdgcn_s_barrier();
    __builtin_amdgcn_sched_barrier(0);

#pragma unroll 16
    for (int i = 0; i < 16; ++i) {
        const unsigned short* Bufc = smem_us + (i % 3) * 12288;
        unsigned short* dbase = smem_us + ((i + 2) % 3) * 12288;
        const unsigned kkn = (unsigned)(((i + 2) & 15) * 32);  // wrap keeps counts uniform

        // issue k(i+2) triple early (lands under the next two MFMA phases)
        glds16(pW0 + kkn, dbase + wstA);
        glds16(pW1 + kkn, dbase + wstA + 512);
        glds16(pX + kkn,  dbase + wstB);

        half8 ah[4], bh[4];
#pragma unroll
        for (int v = 0; v < 4; ++v) ah[v] = *(const half8*)(Bufc + aoffb + v * 512);
#pragma unroll
        for (int u = 0; u < 4; ++u) bh[u] = *(const half8*)(Bufc + boffb + u * 512);
        asm volatile("s_waitcnt lgkmcnt(0)" ::: "memory");
        __builtin_amdgcn_sched_barrier(0);
        __builtin_amdgcn_s_setprio(1);
#pragma unroll
        for (int v = 0; v < 4; ++v)
#pragma unroll
            for (int u = 0; u < 4; ++u)
                acc[v][u] = __builtin_amdgcn_mfma_f32_16x16x32_f16(ah[v], bh[u], acc[v][u], 0, 0, 0);
        __builtin_amdgcn_s_setprio(0);
        asm volatile("s_waitcnt vmcnt(3)" ::: "memory");   // k(i+1) triple landed
        __builtin_amdgcn_s_barrier();
        __builtin_amdgcn_sched_barrier(0);
    }

    // ---------- epilogue ----------
    asm volatile("s_waitcnt vmcnt(0)" ::: "memory");   // drain wrap-staging junk DMAs
    __syncthreads();                     // LDS reused below
    __half* epf = (__half*)smem_us;      // [128 t][72] f16 (64 ch + pad), 144B rows
    __half* epz = epf + 128 * 72;
    __half* epo = epz + 128 * 72;        // total 55,296 B < 72 KiB
    const int ch_base = r0 >> 2;         // 64 channels per block

#pragma unroll
    for (int v = 0; v < 4; ++v) {
        const int cl = wm * 16 + v * 4 + q;          // local channel 0..63
        const int ch = ch_base + cl;
        const float bz  = bias[ch];
        const float bf_ = bias[256 + ch];
        const float bo  = bias[512 + ch];
        const float bi  = bias[768 + ch];
#pragma unroll
        for (int u = 0; u < 4; ++u) {
            const int t_l = wn * 64 + u * 16 + mr;   // local t 0..127
            float zv = ftanh(acc[v][u][0] + bz);
            float fv = fsig(acc[v][u][1] + bf_);
            float ov = fsig(acc[v][u][2] + bo);
            float iv = fsig(acc[v][u][3] + bi);
            const int off = t_l * 72 + cl;
            epf[off] = __float2half(fv);             // same f16 rounding as before
            epz[off] = __float2half(iv * zv);
            epo[off] = __float2half(ov);
        }
    }
    __syncthreads();

    // coalesced f16 stores: 4 threads per t-row, 16 channels (32B) each
    {
        const int t_r = tid >> 2;                    // 0..127
        const int c16 = (tid & 3) << 4;              // 0,16,32,48
        const size_t gbase = ((size_t)bb * T_ + t0 + t_r) * 256 + ch_base + c16;
        const int lb = t_r * 72 + c16;               // 16B-aligned (144|16, 32|16)
        {
            const uint4* s = (const uint4*)&epf[lb];
            uint4* d = (uint4*)&fw[gbase];
            d[0] = s[0]; d[1] = s[1];
        }
        {
            const uint4* s = (const uint4*)&epz[lb];
            uint4* d = (uint4*)&izw[gbase];
            d[0] = s[0]; d[1] = s[1];
        }
        {
            const uint4* s = (const uint4*)&epo[lb];
            uint4* d = (uint4*)&ow[gbase];
            d[0] = s[0]; d[1] = s[1];
        }
    }

    // fused scan phase 1: per-chunk (A = prod f, B = affine end); 4 chunks x 64 ch
    if (tid < 256) {
        const int chunk = tid >> 6;                  // 0..3
        const int c = tid & 63;
        float A = 1.0f, Bv = 0.0f;
        const int base = (chunk * 32) * 72 + c;
#pragma unroll 4
        for (int j = 0; j < 32; ++j) {
            float f  = __half2float(epf[base + j * 72]);
            float iz = __half2float(epz[base + j * 72]);
            Bv = fmaf(f, Bv, iz);
            A *= f;
        }
        const int chunk_abs = (t0 >> 5) + chunk;
        const size_t aidx = ((size_t)bb * NCH + chunk_abs) * 256 + ch_base + c;
        Aw[aidx] = A;
        Bw[aidx] = Bv;
    }
}

// Phase 3: each block computes its own carry from the chunk summaries
// (L2-hot), then replays the recurrence and writes out[b][c][t] transposed
// with float4 stores.
__global__ void scan_phase3(const __half* __restrict__ fw, const __half* __restrict__ izw,
                            const __half* __restrict__ ow,
                            const float* __restrict__ Aw, const float* __restrict__ Bw,
                            float* __restrict__ out)
{
    __shared__ float hbuf[CL][257];
    __shared__ float carry_s[256];
    int b = blockIdx.y, ch = blockIdx.x;
    int tid = threadIdx.x;

    {   // carry over chunks 0..ch-1 for channel tid (exclusive scan, batched)
        const int c = tid;
        float carry = 0.0f;
        for (int g = 0; g < 8; ++g) {
            if (g * 16 >= ch) break;
            float Ar[16], Br[16];
#pragma unroll
            for (int j = 0; j < 16; ++j) {
                int jj = g * 16 + j;
                bool ok = jj < ch;
                size_t idx2 = ((size_t)(b * NCH + (ok ? jj : 0))) * CO + c;
                Ar[j] = ok ? Aw[idx2] : 1.0f;
                Br[j] = ok ? Bw[idx2] : 0.0f;
            }
#pragma unroll
            for (int j = 0; j < 16; ++j) carry = fmaf(Ar[j], carry, Br[j]);
        }
        carry_s[c] = carry;
    }
    __syncthreads();

    if (tid < 128) {
        const int c2 = tid * 2;
        float cs0 = carry_s[c2];
        float cs1 = carry_s[c2 + 1];
        size_t base = ((size_t)(b * T_ + ch * CL)) * CO + c2;
#pragma unroll 4
        for (int tt = 0; tt < CL; tt++) {
            __half2 f2  = *(const __half2*)&fw [base + (size_t)tt * CO];
            __half2 iz2 = *(const __half2*)&izw[base + (size_t)tt * CO];
            __half2 o2  = *(const __half2*)&ow [base + (size_t)tt * CO];
            float2 f  = __half22float2(f2);
            float2 iz = __half22float2(iz2);
            float2 o  = __half22float2(o2);
            cs0 = fmaf(f.x, cs0, iz.x);
            cs1 = fmaf(f.y, cs1, iz.y);
            hbuf[tt][c2]     = o.x * cs0;
            hbuf[tt][c2 + 1] = o.y * cs1;
        }
    }
    __syncthreads();

    // float4 out-stores: thread (tt-group, cc) writes 4 consecutive t
    {
        const int tt4 = (tid & 7) * 4;               // 0,4,...,28
        const int cc0 = tid >> 3;                    // 0..31
#pragma unroll
        for (int w = 0; w < 8; ++w) {
            const int cc = cc0 + w * 32;
            float4 h4;
            h4.x = hbuf[tt4 + 0][cc];
            h4.y = hbuf[tt4 + 1][cc];
            h4.z = hbuf[tt4 + 2][cc];
            h4.w = hbuf[tt4 + 3][cc];
            *(float4*)&out[((size_t)(b * CO + cc)) * T_ + ch * CL + tt4] = h4;
        }
    }
}

extern "C" void kernel_launch(void* const* d_in, const int* in_sizes, int n_in,
                              void* d_out, int out_size, void* d_ws, size_t ws_size,
                              hipStream_t stream) {
    const float* x    = (const float*)d_in[0];
    const float* W    = (const float*)d_in[1];
    const float* bias = (const float*)d_in[2];
    float* out = (float*)d_out;
    float* ws  = (float*)d_ws;

    unsigned short* Xf = (unsigned short*)(ws + OFF_XF);
    unsigned short* Wf = (unsigned short*)(ws + OFF_WF);
    __half* fw  = (__half*)(ws + OFF_F16);
    __half* izw = (__half*)(ws + OFF_IZ16);
    __half* ow  = (__half*)(ws + OFF_O16);
    float* Aw  = ws + OFF_A;
    float* Bw  = ws + OFF_B;

    convert_kernel<<<4096, 256, 0, stream>>>(W, x, Wf, Xf);
    gemm_mfma_kernel<<<(NN / 128) * (O4 / 256), 512, 0, stream>>>(
        Xf, Wf, bias, fw, izw, ow, Aw, Bw);
    scan_phase3<<<dim3(NCH, B_), CO, 0, stream>>>(fw, izw, ow, Aw, Bw, out);
}